// Round 1
// baseline (352.370 us; speedup 1.0000x reference)
//
#include <hip/hip_runtime.h>
#include <hip/hip_bf16.h>

// ---- problem constants ----
#define NTOK 8192      // B*N = 8*1024
#define CDIM 768
#define HIDD 3072
#define NQKV 2304
#define SEQL 1024
#define NHEAD 12

typedef __bf16 bf16x8 __attribute__((ext_vector_type(8)));
typedef float f32x4 __attribute__((ext_vector_type(4)));
typedef unsigned short us8 __attribute__((ext_vector_type(8)));

__device__ __forceinline__ unsigned short f32_to_bf16(float f) {
    unsigned int u = __float_as_uint(f);
    u += 0x7FFFu + ((u >> 16) & 1u);
    return (unsigned short)(u >> 16);
}

// sign(w) as bf16 bits: +1.0 -> 0x3F80, -1.0 -> 0xBF80 (x>=0 -> +1 per ste_sign)
__global__ void sign_w_kernel(const float* __restrict__ w, unsigned short* __restrict__ ws, int n) {
    int i = blockIdx.x * blockDim.x + threadIdx.x;
    int stride = gridDim.x * blockDim.x;
    for (; i < n; i += stride)
        ws[i] = (w[i] >= 0.0f) ? 0x3F80 : 0xBF80;
}

// alpha[row] = mean(|w[row,:]|)
__global__ void __launch_bounds__(256) alpha_kernel(const float* __restrict__ w, float* __restrict__ alpha, int K) {
    int row = blockIdx.x;
    const float* wr = w + (size_t)row * K;
    float s = 0.f;
    for (int i = threadIdx.x; i < K; i += 256) s += fabsf(wr[i]);
    for (int off = 32; off > 0; off >>= 1) s += __shfl_down(s, off);
    __shared__ float red[4];
    if ((threadIdx.x & 63) == 0) red[threadIdx.x >> 6] = s;
    __syncthreads();
    if (threadIdx.x == 0) alpha[row] = (red[0] + red[1] + red[2] + red[3]) / (float)K;
}

// LayerNorm over 768; SIGN_OUT: write sign as bf16 +-1, else bf16 value
template<bool SIGN_OUT>
__global__ void __launch_bounds__(256) ln_kernel(const float* __restrict__ x, const float* __restrict__ g,
                                                 const float* __restrict__ b, unsigned short* __restrict__ out) {
    int row = blockIdx.x;
    const float* xr = x + (size_t)row * CDIM;
    float v0 = xr[threadIdx.x], v1 = xr[threadIdx.x + 256], v2 = xr[threadIdx.x + 512];
    float s = v0 + v1 + v2, s2 = v0 * v0 + v1 * v1 + v2 * v2;
    for (int off = 32; off > 0; off >>= 1) { s += __shfl_down(s, off); s2 += __shfl_down(s2, off); }
    __shared__ float red[8];
    if ((threadIdx.x & 63) == 0) { red[threadIdx.x >> 6] = s; red[4 + (threadIdx.x >> 6)] = s2; }
    __syncthreads();
    float ts = red[0] + red[1] + red[2] + red[3];
    float t2 = red[4] + red[5] + red[6] + red[7];
    float mu = ts * (1.0f / CDIM);
    float var = t2 * (1.0f / CDIM) - mu * mu;
    float rstd = rsqrtf(var + 1e-5f);
    unsigned short* orow = out + (size_t)row * CDIM;
    float vv[3] = {v0, v1, v2};
#pragma unroll
    for (int p = 0; p < 3; p++) {
        int i = threadIdx.x + p * 256;
        float val = (vv[p] - mu) * rstd * g[i] + b[i];
        orow[i] = SIGN_OUT ? ((val >= 0.f) ? 0x3F80 : 0xBF80) : f32_to_bf16(val);
    }
}

// ---------- GEMM: out[M,N] = A[M,K] @ B[N,K]^T, bf16 inputs, f32 accum ----------
// 128x128 tile, 4 waves (2x2), 16x16x32 MFMA, BK=32.
enum { EPI_SIGN = 0, EPI_RESID = 1, EPI_GELU = 2 };

template<int EPI>
__global__ void __launch_bounds__(256) gemm_bt(
    const unsigned short* __restrict__ A, const unsigned short* __restrict__ B,
    int M, int N, int K,
    const float* __restrict__ alpha, const float* __restrict__ bias,
    const float* __restrict__ ls, const float* __restrict__ resid,
    float* __restrict__ outF, unsigned short* __restrict__ outH)
{
    __shared__ unsigned short As[128][40];  // +8 pad (16B) keeps 16B alignment, spreads banks
    __shared__ unsigned short Bs[128][40];
    const int tid = threadIdx.x;
    const int ln = tid & 63, w = tid >> 6;
    const int wm = w >> 1, wn = w & 1;
    const int bm = blockIdx.y * 128, bn = blockIdx.x * 128;

    const f32x4 zero = {0.f, 0.f, 0.f, 0.f};
    f32x4 acc[4][4];
#pragma unroll
    for (int m = 0; m < 4; m++)
#pragma unroll
        for (int n = 0; n < 4; n++) acc[m][n] = zero;

    const int lrow = tid >> 2, lcol = (tid & 3) * 8;

    for (int k0 = 0; k0 < K; k0 += 32) {
        __syncthreads();
#pragma unroll
        for (int p = 0; p < 2; p++) {
            int r = lrow + p * 64;
            us8 av = *(const us8*)(A + (size_t)(bm + r) * K + k0 + lcol);
            us8 bv = *(const us8*)(B + (size_t)(bn + r) * K + k0 + lcol);
            *(us8*)&As[r][lcol] = av;
            *(us8*)&Bs[r][lcol] = bv;
        }
        __syncthreads();
        bf16x8 aF[4], bF[4];
#pragma unroll
        for (int m = 0; m < 4; m++) aF[m] = *(const bf16x8*)&As[wm * 64 + m * 16 + (ln & 15)][8 * (ln >> 4)];
#pragma unroll
        for (int n = 0; n < 4; n++) bF[n] = *(const bf16x8*)&Bs[wn * 64 + n * 16 + (ln & 15)][8 * (ln >> 4)];
#pragma unroll
        for (int m = 0; m < 4; m++)
#pragma unroll
            for (int n = 0; n < 4; n++)
                acc[m][n] = __builtin_amdgcn_mfma_f32_16x16x32_bf16(aF[m], bF[n], acc[m][n], 0, 0, 0);
    }

    // epilogue: C row = (ln>>4)*4 + i, col = ln&15 within each 16x16 frag
    const int r0 = bm + wm * 64, c0 = bn + wn * 64;
#pragma unroll
    for (int m = 0; m < 4; m++) {
#pragma unroll
        for (int n = 0; n < 4; n++) {
            int c = c0 + n * 16 + (ln & 15);
#pragma unroll
            for (int i = 0; i < 4; i++) {
                int r = r0 + m * 16 + (ln >> 4) * 4 + i;
                float v = acc[m][n][i];
                size_t idx = (size_t)r * N + c;
                if (EPI == EPI_SIGN) {
                    outH[idx] = (v >= 0.f) ? 0x3F80 : 0xBF80;
                } else if (EPI == EPI_RESID) {
                    float t = alpha[c] * v + bias[c];
                    outF[idx] = resid[idx] + ls[c] * t;
                } else {  // EPI_GELU
                    float t = alpha[c] * v + bias[c];
                    float ge = 0.5f * t * (1.0f + erff(t * 0.70710678118654752f));
                    outH[idx] = f32_to_bf16(ge);
                }
            }
        }
    }
}

// ---------- binary attention: mask = (Q.K^T > 0); O = mask @ V; emit sign(O) ----------
// block: (qt, bh); 64 q-rows per block, 4 waves x 16 rows; KV tiles of 64.
__global__ void __launch_bounds__(256) attn_kernel(const unsigned short* __restrict__ qkv,
                                                   unsigned short* __restrict__ a2) {
    const int qt = blockIdx.x;   // 0..15
    const int bh = blockIdx.y;   // 0..95
    const int b = bh / NHEAD, h = bh % NHEAD;
    const int n0 = qt * 64;
    const int tid = threadIdx.x, ln = tid & 63, w = tid >> 6;

    __shared__ unsigned short Qs[64][72];
    __shared__ unsigned short Ks[64][72];
    __shared__ unsigned short Vt[64][72];   // transposed: Vt[dim][kv]
    __shared__ unsigned short Ps[64][72];

    const size_t tokbase = (size_t)b * SEQL;

    // stage Q tile (rows n0..n0+63, cols h*64..h*64+63)
    {
        int r = tid >> 2;
#pragma unroll
        for (int p = 0; p < 2; p++) {
            int cc = (tid & 3) * 8 + p * 32;
            us8 v = *(const us8*)(qkv + (tokbase + n0 + r) * NQKV + h * 64 + cc);
            *(us8*)&Qs[r][cc] = v;
        }
    }

    const f32x4 zero = {0.f, 0.f, 0.f, 0.f};
    f32x4 o[4];
#pragma unroll
    for (int d = 0; d < 4; d++) o[d] = zero;

    for (int j = 0; j < 16; j++) {
        __syncthreads();   // also covers initial Q staging on j==0
        {
            int r = tid >> 2;
#pragma unroll
            for (int p = 0; p < 2; p++) {
                int cc = (tid & 3) * 8 + p * 32;
                us8 kv_ = *(const us8*)(qkv + (tokbase + j * 64 + r) * NQKV + 768 + h * 64 + cc);
                *(us8*)&Ks[r][cc] = kv_;
                us8 vv = *(const us8*)(qkv + (tokbase + j * 64 + r) * NQKV + 1536 + h * 64 + cc);
#pragma unroll
                for (int e = 0; e < 8; e++) Vt[cc + e][r] = vv[e];
            }
        }
        __syncthreads();

        bf16x8 qa[2];
#pragma unroll
        for (int ks = 0; ks < 2; ks++) qa[ks] = *(const bf16x8*)&Qs[w * 16 + (ln & 15)][ks * 32 + 8 * (ln >> 4)];

        f32x4 s[4];
#pragma unroll
        for (int n = 0; n < 4; n++) {
            s[n] = zero;
#pragma unroll
            for (int ks = 0; ks < 2; ks++) {
                bf16x8 kb = *(const bf16x8*)&Ks[n * 16 + (ln & 15)][ks * 32 + 8 * (ln >> 4)];
                s[n] = __builtin_amdgcn_mfma_f32_16x16x32_bf16(qa[ks], kb, s[n], 0, 0, 0);
            }
        }
        // P = (S > 0) ? 1 : 0, transposed through LDS (own-wave rows only, no barrier needed)
#pragma unroll
        for (int n = 0; n < 4; n++)
#pragma unroll
            for (int i = 0; i < 4; i++)
                Ps[w * 16 + (ln >> 4) * 4 + i][n * 16 + (ln & 15)] = (s[n][i] > 0.f) ? 0x3F80 : 0;

        bf16x8 pa[2];
#pragma unroll
        for (int ks = 0; ks < 2; ks++) pa[ks] = *(const bf16x8*)&Ps[w * 16 + (ln & 15)][ks * 32 + 8 * (ln >> 4)];
#pragma unroll
        for (int d = 0; d < 4; d++)
#pragma unroll
            for (int ks = 0; ks < 2; ks++) {
                bf16x8 vb = *(const bf16x8*)&Vt[d * 16 + (ln & 15)][ks * 32 + 8 * (ln >> 4)];
                o[d] = __builtin_amdgcn_mfma_f32_16x16x32_bf16(pa[ks], vb, o[d], 0, 0, 0);
            }
    }

    // epilogue: a2[token][h*64+dim] = sign(o)
#pragma unroll
    for (int d = 0; d < 4; d++)
#pragma unroll
        for (int i = 0; i < 4; i++) {
            int qrow = n0 + w * 16 + (ln >> 4) * 4 + i;
            int dim = d * 16 + (ln & 15);
            a2[(tokbase + qrow) * CDIM + h * 64 + dim] = (o[d][i] >= 0.f) ? 0x3F80 : 0xBF80;
        }
}

// ---------- workspace layout (bytes) ----------
// [W signs + alphas | buf1 (qkv / M1 head) | buf3 (A2 / M1 tail) | buf2 (A1 / h2)]
static const size_t OFF_WQKV  = 0;                                   // 2304*768*2 = 3538944
static const size_t OFF_WPROJ = 3538944;                             // 768*768*2  = 1179648
static const size_t OFF_WFC1  = 4718592;                             // 3072*768*2 = 4718592
static const size_t OFF_WFC2  = 9437184;                             // 768*3072*2 = 4718592
static const size_t OFF_APROJ = 14155776;                            // 768*4
static const size_t OFF_AFC1  = 14158848;                            // 3072*4
static const size_t OFF_AFC2  = 14171136;                            // 768*4
static const size_t OFF_BUF1  = 14174208;                            // qkv sign: 8192*2304*2 = 37748736 ; later M1 (50331648 spans buf1+buf3)
static const size_t OFF_BUF3  = 51922944;                            // A2: 8192*768*2 = 12582912
static const size_t OFF_BUF2  = 64505856;                            // A1 / h2: 12582912
// total = 77088768 bytes

extern "C" void kernel_launch(void* const* d_in, const int* in_sizes, int n_in,
                              void* d_out, int out_size, void* d_ws, size_t ws_size,
                              hipStream_t stream) {
    const float* x      = (const float*)d_in[0];
    const float* ln1_g  = (const float*)d_in[1];
    const float* ln1_b  = (const float*)d_in[2];
    const float* w_qkv  = (const float*)d_in[3];
    const float* w_proj = (const float*)d_in[4];
    const float* b_proj = (const float*)d_in[5];
    const float* ls1_g  = (const float*)d_in[6];
    const float* ln2_g  = (const float*)d_in[7];
    const float* ln2_b  = (const float*)d_in[8];
    const float* w_fc1  = (const float*)d_in[9];
    const float* b_fc1  = (const float*)d_in[10];
    const float* w_fc2  = (const float*)d_in[11];
    const float* b_fc2  = (const float*)d_in[12];
    const float* ls2_g  = (const float*)d_in[13];
    float* out = (float*)d_out;

    char* ws = (char*)d_ws;
    unsigned short* wqkv_s  = (unsigned short*)(ws + OFF_WQKV);
    unsigned short* wproj_s = (unsigned short*)(ws + OFF_WPROJ);
    unsigned short* wfc1_s  = (unsigned short*)(ws + OFF_WFC1);
    unsigned short* wfc2_s  = (unsigned short*)(ws + OFF_WFC2);
    float* a_proj = (float*)(ws + OFF_APROJ);
    float* a_fc1  = (float*)(ws + OFF_AFC1);
    float* a_fc2  = (float*)(ws + OFF_AFC2);
    unsigned short* qkv_s = (unsigned short*)(ws + OFF_BUF1);
    unsigned short* m1    = (unsigned short*)(ws + OFF_BUF1);  // reuses qkv + a2 regions
    unsigned short* a2    = (unsigned short*)(ws + OFF_BUF3);
    unsigned short* a1    = (unsigned short*)(ws + OFF_BUF2);
    unsigned short* h2    = (unsigned short*)(ws + OFF_BUF2);

    // weight prep
    sign_w_kernel<<<1024, 256, 0, stream>>>(w_qkv,  wqkv_s,  NQKV * CDIM);
    sign_w_kernel<<<1024, 256, 0, stream>>>(w_proj, wproj_s, CDIM * CDIM);
    sign_w_kernel<<<1024, 256, 0, stream>>>(w_fc1,  wfc1_s,  HIDD * CDIM);
    sign_w_kernel<<<1024, 256, 0, stream>>>(w_fc2,  wfc2_s,  CDIM * HIDD);
    alpha_kernel<<<CDIM, 256, 0, stream>>>(w_proj, a_proj, CDIM);
    alpha_kernel<<<HIDD, 256, 0, stream>>>(w_fc1,  a_fc1,  CDIM);
    alpha_kernel<<<CDIM, 256, 0, stream>>>(w_fc2,  a_fc2,  HIDD);

    // LN1 + sign
    ln_kernel<true><<<NTOK, 256, 0, stream>>>(x, ln1_g, ln1_b, a1);

    // QKV: sign(a1 @ wqkv^T)  (alpha irrelevant under sign since alpha>0)
    gemm_bt<EPI_SIGN><<<dim3(NQKV / 128, NTOK / 128), 256, 0, stream>>>(
        a1, wqkv_s, NTOK, NQKV, CDIM, nullptr, nullptr, nullptr, nullptr, nullptr, qkv_s);

    // binary attention -> sign(O)
    attn_kernel<<<dim3(16, 96), 256, 0, stream>>>(qkv_s, a2);

    // proj + layerscale residual: out(x1) = x + ls1*(alpha_proj*acc + b_proj)
    gemm_bt<EPI_RESID><<<dim3(CDIM / 128, NTOK / 128), 256, 0, stream>>>(
        a2, wproj_s, NTOK, CDIM, CDIM, a_proj, b_proj, ls1_g, x, out, nullptr);

    // LN2 (reads x1 from d_out)
    ln_kernel<false><<<NTOK, 256, 0, stream>>>(out, ln2_g, ln2_b, h2);

    // fc1 + gelu
    gemm_bt<EPI_GELU><<<dim3(HIDD / 128, NTOK / 128), 256, 0, stream>>>(
        h2, wfc1_s, NTOK, HIDD, CDIM, a_fc1, b_fc1, nullptr, nullptr, nullptr, m1);

    // fc2 + layerscale residual (in-place on d_out)
    gemm_bt<EPI_RESID><<<dim3(CDIM / 128, NTOK / 128), 256, 0, stream>>>(
        m1, wfc2_s, NTOK, CDIM, HIDD, a_fc2, b_fc2, ls2_g, out, out, nullptr);
}

// Round 2
// 320.331 us; speedup vs baseline: 1.1000x; 1.1000x over previous
//
#include <hip/hip_runtime.h>
#include <hip/hip_bf16.h>

// ---- problem constants ----
#define NTOK 8192      // B*N = 8*1024
#define CDIM 768
#define HIDD 3072
#define NQKV 2304
#define SEQL 1024
#define NHEAD 12

typedef __bf16 bf16x8 __attribute__((ext_vector_type(8)));
typedef float f32x4 __attribute__((ext_vector_type(4)));
typedef unsigned short us8 __attribute__((ext_vector_type(8)));

__device__ __forceinline__ unsigned short f32_to_bf16(float f) {
    unsigned int u = __float_as_uint(f);
    u += 0x7FFFu + ((u >> 16) & 1u);
    return (unsigned short)(u >> 16);
}

// async global->LDS, 16B per lane. Dest is wave-uniform base + lane*16 (hardware rule);
// we pass per-lane pointers that match exactly that pattern.
__device__ __forceinline__ void gload_lds16(const unsigned short* g, unsigned short* l) {
    __builtin_amdgcn_global_load_lds(
        (const __attribute__((address_space(1))) unsigned int*)g,
        (__attribute__((address_space(3))) unsigned int*)l, 16, 0, 0);
}

// sign(w) as bf16 bits: +1.0 -> 0x3F80, -1.0 -> 0xBF80 (x>=0 -> +1 per ste_sign)
__global__ void sign_w_kernel(const float* __restrict__ w, unsigned short* __restrict__ ws, int n) {
    int i = blockIdx.x * blockDim.x + threadIdx.x;
    int stride = gridDim.x * blockDim.x;
    for (; i < n; i += stride)
        ws[i] = (w[i] >= 0.0f) ? 0x3F80 : 0xBF80;
}

// fused: sign(w) + alpha[row] = mean|w[row,:]|
__global__ void __launch_bounds__(256) signalpha_kernel(const float* __restrict__ w,
                                                        unsigned short* __restrict__ ws,
                                                        float* __restrict__ alpha, int K) {
    int row = blockIdx.x;
    const float* wr = w + (size_t)row * K;
    unsigned short* wsr = ws + (size_t)row * K;
    float s = 0.f;
    for (int i = threadIdx.x; i < K; i += 256) {
        float v = wr[i];
        wsr[i] = (v >= 0.f) ? 0x3F80 : 0xBF80;
        s += fabsf(v);
    }
    for (int off = 32; off > 0; off >>= 1) s += __shfl_down(s, off);
    __shared__ float red[4];
    if ((threadIdx.x & 63) == 0) red[threadIdx.x >> 6] = s;
    __syncthreads();
    if (threadIdx.x == 0) alpha[row] = (red[0] + red[1] + red[2] + red[3]) / (float)K;
}

// LayerNorm over 768; SIGN_OUT: write sign as bf16 +-1, else bf16 value
template<bool SIGN_OUT>
__global__ void __launch_bounds__(256) ln_kernel(const float* __restrict__ x, const float* __restrict__ g,
                                                 const float* __restrict__ b, unsigned short* __restrict__ out) {
    int row = blockIdx.x;
    const float* xr = x + (size_t)row * CDIM;
    float v0 = xr[threadIdx.x], v1 = xr[threadIdx.x + 256], v2 = xr[threadIdx.x + 512];
    float s = v0 + v1 + v2, s2 = v0 * v0 + v1 * v1 + v2 * v2;
    for (int off = 32; off > 0; off >>= 1) { s += __shfl_down(s, off); s2 += __shfl_down(s2, off); }
    __shared__ float red[8];
    if ((threadIdx.x & 63) == 0) { red[threadIdx.x >> 6] = s; red[4 + (threadIdx.x >> 6)] = s2; }
    __syncthreads();
    float ts = red[0] + red[1] + red[2] + red[3];
    float t2 = red[4] + red[5] + red[6] + red[7];
    float mu = ts * (1.0f / CDIM);
    float var = t2 * (1.0f / CDIM) - mu * mu;
    float rstd = rsqrtf(var + 1e-5f);
    unsigned short* orow = out + (size_t)row * CDIM;
    float vv[3] = {v0, v1, v2};
#pragma unroll
    for (int p = 0; p < 3; p++) {
        int i = threadIdx.x + p * 256;
        float val = (vv[p] - mu) * rstd * g[i] + b[i];
        orow[i] = SIGN_OUT ? ((val >= 0.f) ? 0x3F80 : 0xBF80) : f32_to_bf16(val);
    }
}

// ---------- GEMM: out[M,N] = A[M,K] @ B[N,K]^T, bf16 inputs, f32 accum ----------
// m97 structure: 128x128 tile, 4 waves (2x2), 16x16x32 MFMA, BK=32,
// global_load_lds width-16 staging into linear LDS, 2 barriers per K-step.
enum { EPI_SIGN = 0, EPI_RESID = 1, EPI_GELU = 2 };

template<int EPI>
__global__ void __launch_bounds__(256) gemm_bt(
    const unsigned short* __restrict__ A, const unsigned short* __restrict__ B,
    int M, int N, int K,
    const float* __restrict__ alpha, const float* __restrict__ bias,
    const float* __restrict__ ls, const float* __restrict__ resid,
    float* __restrict__ outF, unsigned short* __restrict__ outH)
{
    __shared__ unsigned short As[128][32];  // linear: gload_lds dest must be contiguous
    __shared__ unsigned short Bs[128][32];
    const int tid = threadIdx.x;
    const int ln = tid & 63, w = tid >> 6;
    const int wm = w >> 1, wn = w & 1;

    // XCD-chunked swizzle: nwg divisible by 8 for all our launches.
    const int nwg = gridDim.x * gridDim.y;
    const int id = blockIdx.y * gridDim.x + blockIdx.x;
    const int nid = (id & 7) * (nwg >> 3) + (id >> 3);
    const int bxs = nid % gridDim.x, bys = nid / gridDim.x;
    const int bm = bys * 128, bn = bxs * 128;

    const f32x4 zero = {0.f, 0.f, 0.f, 0.f};
    f32x4 acc[4][4];
#pragma unroll
    for (int m = 0; m < 4; m++)
#pragma unroll
        for (int n = 0; n < 4; n++) acc[m][n] = zero;

    // staging geometry: byte offset within 8KB tile o = (w*2+p)*1024 + ln*16
    // row = o/64 (64B = 32 bf16 per row), colbyte = o%64
    const int o0 = (w * 2) * 1024 + ln * 16;

    for (int k0 = 0; k0 < K; k0 += 32) {
        __syncthreads();   // previous tile fully consumed
#pragma unroll
        for (int p = 0; p < 2; p++) {
            int o = o0 + p * 1024;
            int row = o >> 6, ce = (o & 63) >> 1;   // col in elements
            gload_lds16(A + (size_t)(bm + row) * K + k0 + ce, ((unsigned short*)As) + (o >> 1));
            gload_lds16(B + (size_t)(bn + row) * K + k0 + ce, ((unsigned short*)Bs) + (o >> 1));
        }
        __syncthreads();   // compiler emits vmcnt(0) drain before barrier
        bf16x8 aF[4], bF[4];
#pragma unroll
        for (int m = 0; m < 4; m++) aF[m] = *(const bf16x8*)&As[wm * 64 + m * 16 + (ln & 15)][8 * (ln >> 4)];
#pragma unroll
        for (int n = 0; n < 4; n++) bF[n] = *(const bf16x8*)&Bs[wn * 64 + n * 16 + (ln & 15)][8 * (ln >> 4)];
#pragma unroll
        for (int m = 0; m < 4; m++)
#pragma unroll
            for (int n = 0; n < 4; n++)
                acc[m][n] = __builtin_amdgcn_mfma_f32_16x16x32_bf16(aF[m], bF[n], acc[m][n], 0, 0, 0);
    }

    // epilogue: C row = (ln>>4)*4 + i, col = ln&15 within each 16x16 frag
    const int r0 = bm + wm * 64, c0 = bn + wn * 64;
#pragma unroll
    for (int m = 0; m < 4; m++) {
#pragma unroll
        for (int n = 0; n < 4; n++) {
            int c = c0 + n * 16 + (ln & 15);
#pragma unroll
            for (int i = 0; i < 4; i++) {
                int r = r0 + m * 16 + (ln >> 4) * 4 + i;
                float v = acc[m][n][i];
                size_t idx = (size_t)r * N + c;
                if (EPI == EPI_SIGN) {
                    outH[idx] = (v >= 0.f) ? 0x3F80 : 0xBF80;
                } else if (EPI == EPI_RESID) {
                    float t = alpha[c] * v + bias[c];
                    outF[idx] = resid[idx] + ls[c] * t;
                } else {  // EPI_GELU
                    float t = alpha[c] * v + bias[c];
                    float ge = 0.5f * t * (1.0f + erff(t * 0.70710678118654752f));
                    outH[idx] = f32_to_bf16(ge);
                }
            }
        }
    }
}

// ---------- binary attention: mask = (Q.K^T > 0); O = mask @ V; emit sign(O) ----------
// block: (qt, bh); 64 q-rows per block, 4 waves x 16 rows; KV tiles of 64.
__global__ void __launch_bounds__(256) attn_kernel(const unsigned short* __restrict__ qkv,
                                                   unsigned short* __restrict__ a2) {
    const int qt = blockIdx.x;   // 0..15
    const int bh = blockIdx.y;   // 0..95
    const int b = bh / NHEAD, h = bh % NHEAD;
    const int n0 = qt * 64;
    const int tid = threadIdx.x, ln = tid & 63, w = tid >> 6;

    __shared__ unsigned short Qs[64][72];
    __shared__ unsigned short Ks[64][72];
    __shared__ unsigned short Vt[64][72];   // transposed: Vt[dim][kv]
    __shared__ unsigned short Ps[64][72];

    const size_t tokbase = (size_t)b * SEQL;

    // stage Q tile (rows n0..n0+63, cols h*64..h*64+63)
    {
        int r = tid >> 2;
#pragma unroll
        for (int p = 0; p < 2; p++) {
            int cc = (tid & 3) * 8 + p * 32;
            us8 v = *(const us8*)(qkv + (tokbase + n0 + r) * NQKV + h * 64 + cc);
            *(us8*)&Qs[r][cc] = v;
        }
    }

    const f32x4 zero = {0.f, 0.f, 0.f, 0.f};
    f32x4 o[4];
#pragma unroll
    for (int d = 0; d < 4; d++) o[d] = zero;

    for (int j = 0; j < 16; j++) {
        __syncthreads();   // also covers initial Q staging on j==0
        {
            int r = tid >> 2;
#pragma unroll
            for (int p = 0; p < 2; p++) {
                int cc = (tid & 3) * 8 + p * 32;
                us8 kv_ = *(const us8*)(qkv + (tokbase + j * 64 + r) * NQKV + 768 + h * 64 + cc);
                *(us8*)&Ks[r][cc] = kv_;
                us8 vv = *(const us8*)(qkv + (tokbase + j * 64 + r) * NQKV + 1536 + h * 64 + cc);
#pragma unroll
                for (int e = 0; e < 8; e++) Vt[cc + e][r] = vv[e];
            }
        }
        __syncthreads();

        bf16x8 qa[2];
#pragma unroll
        for (int ks = 0; ks < 2; ks++) qa[ks] = *(const bf16x8*)&Qs[w * 16 + (ln & 15)][ks * 32 + 8 * (ln >> 4)];

        f32x4 s[4];
#pragma unroll
        for (int n = 0; n < 4; n++) {
            s[n] = zero;
#pragma unroll
            for (int ks = 0; ks < 2; ks++) {
                bf16x8 kb = *(const bf16x8*)&Ks[n * 16 + (ln & 15)][ks * 32 + 8 * (ln >> 4)];
                s[n] = __builtin_amdgcn_mfma_f32_16x16x32_bf16(qa[ks], kb, s[n], 0, 0, 0);
            }
        }
        // P = (S > 0) ? 1 : 0, transposed through LDS (own-wave rows only, no barrier needed)
#pragma unroll
        for (int n = 0; n < 4; n++)
#pragma unroll
            for (int i = 0; i < 4; i++)
                Ps[w * 16 + (ln >> 4) * 4 + i][n * 16 + (ln & 15)] = (s[n][i] > 0.f) ? 0x3F80 : 0;

        bf16x8 pa[2];
#pragma unroll
        for (int ks = 0; ks < 2; ks++) pa[ks] = *(const bf16x8*)&Ps[w * 16 + (ln & 15)][ks * 32 + 8 * (ln >> 4)];
#pragma unroll
        for (int d = 0; d < 4; d++)
#pragma unroll
            for (int ks = 0; ks < 2; ks++) {
                bf16x8 vb = *(const bf16x8*)&Vt[d * 16 + (ln & 15)][ks * 32 + 8 * (ln >> 4)];
                o[d] = __builtin_amdgcn_mfma_f32_16x16x32_bf16(pa[ks], vb, o[d], 0, 0, 0);
            }
    }

    // epilogue: a2[token][h*64+dim] = sign(o)
#pragma unroll
    for (int d = 0; d < 4; d++)
#pragma unroll
        for (int i = 0; i < 4; i++) {
            int qrow = n0 + w * 16 + (ln >> 4) * 4 + i;
            int dim = d * 16 + (ln & 15);
            a2[(tokbase + qrow) * CDIM + h * 64 + dim] = (o[d][i] >= 0.f) ? 0x3F80 : 0xBF80;
        }
}

// ---------- workspace layout (bytes) ----------
static const size_t OFF_WQKV  = 0;                                   // 2304*768*2 = 3538944
static const size_t OFF_WPROJ = 3538944;                             // 768*768*2  = 1179648
static const size_t OFF_WFC1  = 4718592;                             // 3072*768*2 = 4718592
static const size_t OFF_WFC2  = 9437184;                             // 768*3072*2 = 4718592
static const size_t OFF_APROJ = 14155776;                            // 768*4
static const size_t OFF_AFC1  = 14158848;                            // 3072*4
static const size_t OFF_AFC2  = 14171136;                            // 768*4
static const size_t OFF_BUF1  = 14174208;                            // qkv sign: 8192*2304*2 ; later M1 (spans buf1+buf3)
static const size_t OFF_BUF3  = 51922944;                            // A2: 8192*768*2 = 12582912
static const size_t OFF_BUF2  = 64505856;                            // A1 / h2: 12582912
// total = 77088768 bytes

extern "C" void kernel_launch(void* const* d_in, const int* in_sizes, int n_in,
                              void* d_out, int out_size, void* d_ws, size_t ws_size,
                              hipStream_t stream) {
    const float* x      = (const float*)d_in[0];
    const float* ln1_g  = (const float*)d_in[1];
    const float* ln1_b  = (const float*)d_in[2];
    const float* w_qkv  = (const float*)d_in[3];
    const float* w_proj = (const float*)d_in[4];
    const float* b_proj = (const float*)d_in[5];
    const float* ls1_g  = (const float*)d_in[6];
    const float* ln2_g  = (const float*)d_in[7];
    const float* ln2_b  = (const float*)d_in[8];
    const float* w_fc1  = (const float*)d_in[9];
    const float* b_fc1  = (const float*)d_in[10];
    const float* w_fc2  = (const float*)d_in[11];
    const float* b_fc2  = (const float*)d_in[12];
    const float* ls2_g  = (const float*)d_in[13];
    float* out = (float*)d_out;

    char* ws = (char*)d_ws;
    unsigned short* wqkv_s  = (unsigned short*)(ws + OFF_WQKV);
    unsigned short* wproj_s = (unsigned short*)(ws + OFF_WPROJ);
    unsigned short* wfc1_s  = (unsigned short*)(ws + OFF_WFC1);
    unsigned short* wfc2_s  = (unsigned short*)(ws + OFF_WFC2);
    float* a_proj = (float*)(ws + OFF_APROJ);
    float* a_fc1  = (float*)(ws + OFF_AFC1);
    float* a_fc2  = (float*)(ws + OFF_AFC2);
    unsigned short* qkv_s = (unsigned short*)(ws + OFF_BUF1);
    unsigned short* m1    = (unsigned short*)(ws + OFF_BUF1);  // reuses qkv + a2 regions
    unsigned short* a2    = (unsigned short*)(ws + OFF_BUF3);
    unsigned short* a1    = (unsigned short*)(ws + OFF_BUF2);
    unsigned short* h2    = (unsigned short*)(ws + OFF_BUF2);

    // weight prep
    sign_w_kernel<<<1024, 256, 0, stream>>>(w_qkv, wqkv_s, NQKV * CDIM);
    signalpha_kernel<<<CDIM, 256, 0, stream>>>(w_proj, wproj_s, a_proj, CDIM);
    signalpha_kernel<<<HIDD, 256, 0, stream>>>(w_fc1,  wfc1_s,  a_fc1,  CDIM);
    signalpha_kernel<<<CDIM, 256, 0, stream>>>(w_fc2,  wfc2_s,  a_fc2,  HIDD);

    // LN1 + sign
    ln_kernel<true><<<NTOK, 256, 0, stream>>>(x, ln1_g, ln1_b, a1);

    // QKV: sign(a1 @ wqkv^T)  (alpha irrelevant under sign since alpha>0)
    gemm_bt<EPI_SIGN><<<dim3(NQKV / 128, NTOK / 128), 256, 0, stream>>>(
        a1, wqkv_s, NTOK, NQKV, CDIM, nullptr, nullptr, nullptr, nullptr, nullptr, qkv_s);

    // binary attention -> sign(O)
    attn_kernel<<<dim3(16, 96), 256, 0, stream>>>(qkv_s, a2);

    // proj + layerscale residual: out(x1) = x + ls1*(alpha_proj*acc + b_proj)
    gemm_bt<EPI_RESID><<<dim3(CDIM / 128, NTOK / 128), 256, 0, stream>>>(
        a2, wproj_s, NTOK, CDIM, CDIM, a_proj, b_proj, ls1_g, x, out, nullptr);

    // LN2 (reads x1 from d_out)
    ln_kernel<false><<<NTOK, 256, 0, stream>>>(out, ln2_g, ln2_b, h2);

    // fc1 + gelu
    gemm_bt<EPI_GELU><<<dim3(HIDD / 128, NTOK / 128), 256, 0, stream>>>(
        h2, wfc1_s, NTOK, HIDD, CDIM, a_fc1, b_fc1, nullptr, nullptr, nullptr, m1);

    // fc2 + layerscale residual (in-place on d_out)
    gemm_bt<EPI_RESID><<<dim3(CDIM / 128, NTOK / 128), 256, 0, stream>>>(
        m1, wfc2_s, NTOK, CDIM, HIDD, a_fc2, b_fc2, ls2_g, out, out, nullptr);
}

// Round 3
// 216.356 us; speedup vs baseline: 1.6287x; 1.4806x over previous
//
#include <hip/hip_runtime.h>

// ---- problem constants ----
#define NTOK 8192      // B*N = 8*1024
#define CDIM 768
#define HIDD 3072
#define NQKV 2304
#define SEQL 1024
#define NHEAD 12

typedef int i32x4 __attribute__((ext_vector_type(4)));
typedef signed char sc16 __attribute__((ext_vector_type(16)));

// async global->LDS, 16B per lane. Dest must be wave-uniform base + lane*16.
__device__ __forceinline__ void gload_lds16(const void* g, void* l) {
    __builtin_amdgcn_global_load_lds(
        (const __attribute__((address_space(1))) unsigned int*)g,
        (__attribute__((address_space(3))) unsigned int*)l, 16, 0, 0);
}

// sign(w) as i8 +-1 (x>=0 -> +1 per ste_sign)
__global__ void sign_w_kernel(const float* __restrict__ w, signed char* __restrict__ ws, int n) {
    int i = blockIdx.x * blockDim.x + threadIdx.x;
    int stride = gridDim.x * blockDim.x;
    for (; i < n; i += stride)
        ws[i] = (w[i] >= 0.0f) ? 1 : -1;
}

// fused: sign(w) i8 + alpha[row] = mean|w[row,:]|
__global__ void __launch_bounds__(256) signalpha_kernel(const float* __restrict__ w,
                                                        signed char* __restrict__ ws,
                                                        float* __restrict__ alpha, int K) {
    int row = blockIdx.x;
    const float* wr = w + (size_t)row * K;
    signed char* wsr = ws + (size_t)row * K;
    float s = 0.f;
    for (int i = threadIdx.x; i < K; i += 256) {
        float v = wr[i];
        wsr[i] = (v >= 0.f) ? 1 : -1;
        s += fabsf(v);
    }
    for (int off = 32; off > 0; off >>= 1) s += __shfl_down(s, off);
    __shared__ float red[4];
    if ((threadIdx.x & 63) == 0) red[threadIdx.x >> 6] = s;
    __syncthreads();
    if (threadIdx.x == 0) alpha[row] = (red[0] + red[1] + red[2] + red[3]) / (float)K;
}

// LayerNorm over 768 -> sign as i8 +-1 (for LN1 path)
__global__ void __launch_bounds__(256) ln_sign_kernel(const float* __restrict__ x, const float* __restrict__ g,
                                                      const float* __restrict__ b, signed char* __restrict__ out) {
    int row = blockIdx.x;
    const float* xr = x + (size_t)row * CDIM;
    float v0 = xr[threadIdx.x], v1 = xr[threadIdx.x + 256], v2 = xr[threadIdx.x + 512];
    float s = v0 + v1 + v2, s2 = v0 * v0 + v1 * v1 + v2 * v2;
    for (int off = 32; off > 0; off >>= 1) { s += __shfl_down(s, off); s2 += __shfl_down(s2, off); }
    __shared__ float red[8];
    if ((threadIdx.x & 63) == 0) { red[threadIdx.x >> 6] = s; red[4 + (threadIdx.x >> 6)] = s2; }
    __syncthreads();
    float ts = red[0] + red[1] + red[2] + red[3];
    float t2 = red[4] + red[5] + red[6] + red[7];
    float mu = ts * (1.0f / CDIM);
    float var = t2 * (1.0f / CDIM) - mu * mu;
    float rstd = rsqrtf(var + 1e-5f);
    signed char* orow = out + (size_t)row * CDIM;
    float vv[3] = {v0, v1, v2};
#pragma unroll
    for (int p = 0; p < 3; p++) {
        int i = threadIdx.x + p * 256;
        float val = (vv[p] - mu) * rstd * g[i] + b[i];
        orow[i] = (val >= 0.f) ? 1 : -1;
    }
}

// LayerNorm over 768 -> per-row i8 quant (for LN2/fc1 path); rowscale[row] = rowmax/127
__global__ void __launch_bounds__(256) ln2q_kernel(const float* __restrict__ x, const float* __restrict__ g,
                                                   const float* __restrict__ b, signed char* __restrict__ out,
                                                   float* __restrict__ rowscale) {
    int row = blockIdx.x;
    const float* xr = x + (size_t)row * CDIM;
    float v0 = xr[threadIdx.x], v1 = xr[threadIdx.x + 256], v2 = xr[threadIdx.x + 512];
    float s = v0 + v1 + v2, s2 = v0 * v0 + v1 * v1 + v2 * v2;
    for (int off = 32; off > 0; off >>= 1) { s += __shfl_down(s, off); s2 += __shfl_down(s2, off); }
    __shared__ float red[8];
    __shared__ float redm[4];
    if ((threadIdx.x & 63) == 0) { red[threadIdx.x >> 6] = s; red[4 + (threadIdx.x >> 6)] = s2; }
    __syncthreads();
    float ts = red[0] + red[1] + red[2] + red[3];
    float t2 = red[4] + red[5] + red[6] + red[7];
    float mu = ts * (1.0f / CDIM);
    float var = t2 * (1.0f / CDIM) - mu * mu;
    float rstd = rsqrtf(var + 1e-5f);
    float a0 = (v0 - mu) * rstd * g[threadIdx.x] + b[threadIdx.x];
    float a1 = (v1 - mu) * rstd * g[threadIdx.x + 256] + b[threadIdx.x + 256];
    float a2v = (v2 - mu) * rstd * g[threadIdx.x + 512] + b[threadIdx.x + 512];
    float mx = fmaxf(fabsf(a0), fmaxf(fabsf(a1), fabsf(a2v)));
    for (int off = 32; off > 0; off >>= 1) mx = fmaxf(mx, __shfl_down(mx, off));
    if ((threadIdx.x & 63) == 0) redm[threadIdx.x >> 6] = mx;
    __syncthreads();
    float rmax = fmaxf(fmaxf(redm[0], redm[1]), fmaxf(redm[2], redm[3]));
    rmax = fmaxf(rmax, 1e-20f);
    float inv = 127.f / rmax;
    signed char* orow = out + (size_t)row * CDIM;
    orow[threadIdx.x]       = (signed char)__float2int_rn(a0 * inv);
    orow[threadIdx.x + 256] = (signed char)__float2int_rn(a1 * inv);
    orow[threadIdx.x + 512] = (signed char)__float2int_rn(a2v * inv);
    if (threadIdx.x == 0) rowscale[row] = rmax * (1.f / 127.f);
}

// ---------- i8 GEMM: acc[M,N] = A[M,K] @ B[N,K]^T, i32 accum ----------
// 128xBN tile, 4 waves, 16x16x64 i8 MFMA, BK=64 bytes, global_load_lds staging.
enum { EPI_SIGN = 0, EPI_RESID = 1, EPI_GELU = 2 };
#define MSCALE_INV 16.0f    // gelu-out quant: q = round(ge*16), dequant acc * (1/16)

template<int EPI, int BN>
__global__ void __launch_bounds__(256) gemm_i8(
    const signed char* __restrict__ A, const signed char* __restrict__ B,
    int M, int N, int K,
    const float* __restrict__ alpha, const float* __restrict__ bias,
    const float* __restrict__ ls, const float* __restrict__ resid,
    const float* __restrict__ rowscale, float ascale,
    float* __restrict__ outF, signed char* __restrict__ outB)
{
    __shared__ signed char As[128][64];
    __shared__ signed char Bs[BN][64];
    const int tid = threadIdx.x, ln = tid & 63, w = tid >> 6;
    const int wm = w >> 1, wn = w & 1;
    constexpr int NF = BN / 32;   // n-frags per wave

    // XCD-chunked bijective swizzle (all grids divisible by 8)
    const int nwg = gridDim.x * gridDim.y;
    const int id = blockIdx.y * gridDim.x + blockIdx.x;
    const int nid = (id & 7) * (nwg >> 3) + (id >> 3);
    const int bxs = nid % gridDim.x, bys = nid / gridDim.x;
    const int bm = bys * 128, bn = bxs * BN;

    const i32x4 iz = {0, 0, 0, 0};
    i32x4 acc[4][NF];
#pragma unroll
    for (int m = 0; m < 4; m++)
#pragma unroll
        for (int n = 0; n < NF; n++) acc[m][n] = iz;

    const int srow = tid >> 2, scol = (tid & 3) * 16;

    for (int k0 = 0; k0 < K; k0 += 64) {
        __syncthreads();
        gload_lds16(A + (size_t)(bm + srow) * K + k0 + scol, &As[srow][scol]);
        gload_lds16(A + (size_t)(bm + 64 + srow) * K + k0 + scol, &As[64 + srow][scol]);
        gload_lds16(B + (size_t)(bn + srow) * K + k0 + scol, &Bs[srow][scol]);
        if constexpr (BN == 128)
            gload_lds16(B + (size_t)(bn + 64 + srow) * K + k0 + scol, &Bs[64 + srow][scol]);
        __syncthreads();
        i32x4 aF[4], bF[NF];
#pragma unroll
        for (int m = 0; m < 4; m++) aF[m] = *(const i32x4*)&As[wm * 64 + m * 16 + (ln & 15)][16 * (ln >> 4)];
#pragma unroll
        for (int n = 0; n < NF; n++) bF[n] = *(const i32x4*)&Bs[wn * (BN / 2) + n * 16 + (ln & 15)][16 * (ln >> 4)];
#pragma unroll
        for (int m = 0; m < 4; m++)
#pragma unroll
            for (int n = 0; n < NF; n++)
                acc[m][n] = __builtin_amdgcn_mfma_i32_16x16x64_i8(aF[m], bF[n], acc[m][n], 0, 0, 0);
    }

    const int r0 = bm + wm * 64, c0 = bn + wn * (BN / 2);
#pragma unroll
    for (int m = 0; m < 4; m++) {
#pragma unroll
        for (int n = 0; n < NF; n++) {
            int c = c0 + n * 16 + (ln & 15);
#pragma unroll
            for (int i = 0; i < 4; i++) {
                int r = r0 + m * 16 + (ln >> 4) * 4 + i;
                int v = acc[m][n][i];
                size_t idx = (size_t)r * N + c;
                if (EPI == EPI_SIGN) {
                    outB[idx] = (v >= 0) ? 1 : -1;
                } else if (EPI == EPI_RESID) {
                    float t = alpha[c] * ((float)v * ascale) + bias[c];
                    outF[idx] = resid[idx] + ls[c] * t;
                } else {  // EPI_GELU: per-row dequant, gelu, fixed-scale i8 quant
                    float t = alpha[c] * ((float)v * rowscale[r]) + bias[c];
                    float ge = 0.5f * t * (1.0f + erff(t * 0.70710678118654752f));
                    float qf = fminf(fmaxf(ge * MSCALE_INV, -127.f), 127.f);
                    outB[idx] = (signed char)__float2int_rn(qf);
                }
            }
        }
    }
}

// ---------- binary attention (i8, exact): mask = (Q.K^T > 0); O = mask @ V; emit sign(O) ----------
__global__ void __launch_bounds__(256) attn_i8(const signed char* __restrict__ qkv,
                                               signed char* __restrict__ a2) {
    // XCD swizzle: all 16 q-tiles of one head land on the same XCD chunk
    const int id = blockIdx.x;                       // 0..1535
    const int nid = (id & 7) * 192 + (id >> 3);
    const int qt = nid & 15;
    const int bh = nid >> 4;
    const int b = bh / NHEAD, h = bh % NHEAD;
    const int n0 = qt * 64;
    const int tid = threadIdx.x, ln = tid & 63, w = tid >> 6;

    __shared__ signed char Qs[64][96];   // 96B stride: 16B-aligned rows, 4-way-max banks
    __shared__ signed char Ks[64][96];
    __shared__ signed char Vt[64][96];   // transposed: Vt[dim][kv]
    __shared__ signed char Ps[64][96];

    const size_t tokbase = (size_t)b * SEQL;
    const int r = tid >> 2, cc = (tid & 3) * 16;

    {   // stage Q tile once
        sc16 v = *(const sc16*)(qkv + (tokbase + n0 + r) * NQKV + h * 64 + cc);
        *(sc16*)&Qs[r][cc] = v;
    }

    const i32x4 iz = {0, 0, 0, 0};
    i32x4 o[4] = {iz, iz, iz, iz};

    for (int j = 0; j < 16; j++) {
        __syncthreads();   // protects Ks/Vt reuse; also covers initial Q staging on j==0
        {
            sc16 kv_ = *(const sc16*)(qkv + (tokbase + j * 64 + r) * NQKV + 768 + h * 64 + cc);
            *(sc16*)&Ks[r][cc] = kv_;
            sc16 vv = *(const sc16*)(qkv + (tokbase + j * 64 + r) * NQKV + 1536 + h * 64 + cc);
#pragma unroll
            for (int e = 0; e < 16; e++) Vt[cc + e][r] = vv[e];
        }
        __syncthreads();

        i32x4 qa = *(const i32x4*)&Qs[w * 16 + (ln & 15)][16 * (ln >> 4)];
#pragma unroll
        for (int n = 0; n < 4; n++) {
            i32x4 kb = *(const i32x4*)&Ks[n * 16 + (ln & 15)][16 * (ln >> 4)];
            i32x4 s = __builtin_amdgcn_mfma_i32_16x16x64_i8(qa, kb, iz, 0, 0, 0);
#pragma unroll
            for (int i = 0; i < 4; i++)
                Ps[w * 16 + (ln >> 4) * 4 + i][n * 16 + (ln & 15)] = (s[i] > 0) ? 1 : 0;
        }
        i32x4 pa = *(const i32x4*)&Ps[w * 16 + (ln & 15)][16 * (ln >> 4)];
#pragma unroll
        for (int d = 0; d < 4; d++) {
            i32x4 vb = *(const i32x4*)&Vt[d * 16 + (ln & 15)][16 * (ln >> 4)];
            o[d] = __builtin_amdgcn_mfma_i32_16x16x64_i8(pa, vb, o[d], 0, 0, 0);
        }
    }

#pragma unroll
    for (int d = 0; d < 4; d++)
#pragma unroll
        for (int i = 0; i < 4; i++) {
            int qrow = n0 + w * 16 + (ln >> 4) * 4 + i;
            int dim = d * 16 + (ln & 15);
            a2[(tokbase + qrow) * CDIM + h * 64 + dim] = (o[d][i] >= 0) ? 1 : -1;
        }
}

// ---------- workspace layout (bytes) ----------
static const size_t OFF_WQKV  = 0;          // 2304*768   = 1769472
static const size_t OFF_WPROJ = 1769472;    // 768*768    = 589824
static const size_t OFF_WFC1  = 2359296;    // 3072*768   = 2359296
static const size_t OFF_WFC2  = 4718592;    // 768*3072   = 2359296
static const size_t OFF_APROJ = 7077888;    // 768*4
static const size_t OFF_AFC1  = 7080960;    // 3072*4
static const size_t OFF_AFC2  = 7093248;    // 768*4
static const size_t OFF_H2SC  = 7096320;    // 8192*4
static const size_t OFF_QKV   = 7129088;    // 8192*2304  = 18874368
static const size_t OFF_A2    = 26003456;   // 8192*768   = 6291456
static const size_t OFF_A1    = 32294912;   // 8192*768   = 6291456
static const size_t OFF_M1    = 38586368;   // 8192*3072  = 25165824
static const size_t OFF_H2    = 63752192;   // 8192*768   = 6291456
// total = 70043648 bytes

extern "C" void kernel_launch(void* const* d_in, const int* in_sizes, int n_in,
                              void* d_out, int out_size, void* d_ws, size_t ws_size,
                              hipStream_t stream) {
    const float* x      = (const float*)d_in[0];
    const float* ln1_g  = (const float*)d_in[1];
    const float* ln1_b  = (const float*)d_in[2];
    const float* w_qkv  = (const float*)d_in[3];
    const float* w_proj = (const float*)d_in[4];
    const float* b_proj = (const float*)d_in[5];
    const float* ls1_g  = (const float*)d_in[6];
    const float* ln2_g  = (const float*)d_in[7];
    const float* ln2_b  = (const float*)d_in[8];
    const float* w_fc1  = (const float*)d_in[9];
    const float* b_fc1  = (const float*)d_in[10];
    const float* w_fc2  = (const float*)d_in[11];
    const float* b_fc2  = (const float*)d_in[12];
    const float* ls2_g  = (const float*)d_in[13];
    float* out = (float*)d_out;

    char* ws = (char*)d_ws;
    signed char* wqkv_s  = (signed char*)(ws + OFF_WQKV);
    signed char* wproj_s = (signed char*)(ws + OFF_WPROJ);
    signed char* wfc1_s  = (signed char*)(ws + OFF_WFC1);
    signed char* wfc2_s  = (signed char*)(ws + OFF_WFC2);
    float* a_proj  = (float*)(ws + OFF_APROJ);
    float* a_fc1   = (float*)(ws + OFF_AFC1);
    float* a_fc2   = (float*)(ws + OFF_AFC2);
    float* h2scale = (float*)(ws + OFF_H2SC);
    signed char* qkv_s = (signed char*)(ws + OFF_QKV);
    signed char* a2    = (signed char*)(ws + OFF_A2);
    signed char* a1    = (signed char*)(ws + OFF_A1);
    signed char* m1    = (signed char*)(ws + OFF_M1);
    signed char* h2    = (signed char*)(ws + OFF_H2);

    // weight prep
    sign_w_kernel<<<512, 256, 0, stream>>>(w_qkv, wqkv_s, NQKV * CDIM);
    signalpha_kernel<<<CDIM, 256, 0, stream>>>(w_proj, wproj_s, a_proj, CDIM);
    signalpha_kernel<<<HIDD, 256, 0, stream>>>(w_fc1,  wfc1_s,  a_fc1,  CDIM);
    signalpha_kernel<<<CDIM, 256, 0, stream>>>(w_fc2,  wfc2_s,  a_fc2,  HIDD);

    // LN1 + sign
    ln_sign_kernel<<<NTOK, 256, 0, stream>>>(x, ln1_g, ln1_b, a1);

    // QKV: sign(a1 @ wqkv^T)  (exact i8; alpha>0 irrelevant under sign)
    gemm_i8<EPI_SIGN, 128><<<dim3(NQKV / 128, NTOK / 128), 256, 0, stream>>>(
        a1, wqkv_s, NTOK, NQKV, CDIM, nullptr, nullptr, nullptr, nullptr, nullptr, 1.0f, nullptr, qkv_s);

    // binary attention -> sign(O) (exact i8)
    attn_i8<<<16 * 96, 256, 0, stream>>>(qkv_s, a2);

    // proj + layerscale residual: out(x1) = x + ls1*(alpha_proj*acc + b_proj)   (acc exact)
    gemm_i8<EPI_RESID, 64><<<dim3(CDIM / 64, NTOK / 128), 256, 0, stream>>>(
        a2, wproj_s, NTOK, CDIM, CDIM, a_proj, b_proj, ls1_g, x, nullptr, 1.0f, out, nullptr);

    // LN2 + per-row i8 quant (reads x1 from d_out)
    ln2q_kernel<<<NTOK, 256, 0, stream>>>(out, ln2_g, ln2_b, h2, h2scale);

    // fc1 + gelu -> fixed-scale i8
    gemm_i8<EPI_GELU, 128><<<dim3(HIDD / 128, NTOK / 128), 256, 0, stream>>>(
        h2, wfc1_s, NTOK, HIDD, CDIM, a_fc1, b_fc1, nullptr, nullptr, h2scale, 1.0f, nullptr, m1);

    // fc2 + layerscale residual (in-place on d_out); dequant by 1/16
    gemm_i8<EPI_RESID, 64><<<dim3(CDIM / 64, NTOK / 128), 256, 0, stream>>>(
        m1, wfc2_s, NTOK, CDIM, HIDD, a_fc2, b_fc2, ls2_g, out, nullptr, 1.0f / MSCALE_INV, out, nullptr);
}

// Round 4
// 209.439 us; speedup vs baseline: 1.6824x; 1.0330x over previous
//
#include <hip/hip_runtime.h>

// ---- problem constants ----
#define NTOK 8192      // B*N = 8*1024
#define CDIM 768
#define HIDD 3072
#define NQKV 2304
#define SEQL 1024
#define NHEAD 12

typedef int i32x4 __attribute__((ext_vector_type(4)));
typedef signed char sc16 __attribute__((ext_vector_type(16)));

// async global->LDS, 16B per lane. Dest must be wave-uniform base + lane*16.
__device__ __forceinline__ void gload_lds16(const void* g, void* l) {
    __builtin_amdgcn_global_load_lds(
        (const __attribute__((address_space(1))) unsigned int*)g,
        (__attribute__((address_space(3))) unsigned int*)l, 16, 0, 0);
}

// sign(w) as i8 +-1 (x>=0 -> +1 per ste_sign)
__global__ void sign_w_kernel(const float* __restrict__ w, signed char* __restrict__ ws, int n) {
    int i = blockIdx.x * blockDim.x + threadIdx.x;
    int stride = gridDim.x * blockDim.x;
    for (; i < n; i += stride)
        ws[i] = (w[i] >= 0.0f) ? 1 : -1;
}

// fused: sign(w) i8 + alpha[row] = mean|w[row,:]|
__global__ void __launch_bounds__(256) signalpha_kernel(const float* __restrict__ w,
                                                        signed char* __restrict__ ws,
                                                        float* __restrict__ alpha, int K) {
    int row = blockIdx.x;
    const float* wr = w + (size_t)row * K;
    signed char* wsr = ws + (size_t)row * K;
    float s = 0.f;
    for (int i = threadIdx.x; i < K; i += 256) {
        float v = wr[i];
        wsr[i] = (v >= 0.f) ? 1 : -1;
        s += fabsf(v);
    }
    for (int off = 32; off > 0; off >>= 1) s += __shfl_down(s, off);
    __shared__ float red[4];
    if ((threadIdx.x & 63) == 0) red[threadIdx.x >> 6] = s;
    __syncthreads();
    if (threadIdx.x == 0) alpha[row] = (red[0] + red[1] + red[2] + red[3]) / (float)K;
}

// LayerNorm over 768 -> sign as i8 +-1 (for LN1 path)
__global__ void __launch_bounds__(256) ln_sign_kernel(const float* __restrict__ x, const float* __restrict__ g,
                                                      const float* __restrict__ b, signed char* __restrict__ out) {
    int row = blockIdx.x;
    const float* xr = x + (size_t)row * CDIM;
    float v0 = xr[threadIdx.x], v1 = xr[threadIdx.x + 256], v2 = xr[threadIdx.x + 512];
    float s = v0 + v1 + v2, s2 = v0 * v0 + v1 * v1 + v2 * v2;
    for (int off = 32; off > 0; off >>= 1) { s += __shfl_down(s, off); s2 += __shfl_down(s2, off); }
    __shared__ float red[8];
    if ((threadIdx.x & 63) == 0) { red[threadIdx.x >> 6] = s; red[4 + (threadIdx.x >> 6)] = s2; }
    __syncthreads();
    float ts = red[0] + red[1] + red[2] + red[3];
    float t2 = red[4] + red[5] + red[6] + red[7];
    float mu = ts * (1.0f / CDIM);
    float var = t2 * (1.0f / CDIM) - mu * mu;
    float rstd = rsqrtf(var + 1e-5f);
    signed char* orow = out + (size_t)row * CDIM;
    float vv[3] = {v0, v1, v2};
#pragma unroll
    for (int p = 0; p < 3; p++) {
        int i = threadIdx.x + p * 256;
        float val = (vv[p] - mu) * rstd * g[i] + b[i];
        orow[i] = (val >= 0.f) ? 1 : -1;
    }
}

// LayerNorm over 768 -> per-row i8 quant (for LN2/fc1 path); rowscale[row] = rowmax/127
__global__ void __launch_bounds__(256) ln2q_kernel(const float* __restrict__ x, const float* __restrict__ g,
                                                   const float* __restrict__ b, signed char* __restrict__ out,
                                                   float* __restrict__ rowscale) {
    int row = blockIdx.x;
    const float* xr = x + (size_t)row * CDIM;
    float v0 = xr[threadIdx.x], v1 = xr[threadIdx.x + 256], v2 = xr[threadIdx.x + 512];
    float s = v0 + v1 + v2, s2 = v0 * v0 + v1 * v1 + v2 * v2;
    for (int off = 32; off > 0; off >>= 1) { s += __shfl_down(s, off); s2 += __shfl_down(s2, off); }
    __shared__ float red[8];
    __shared__ float redm[4];
    if ((threadIdx.x & 63) == 0) { red[threadIdx.x >> 6] = s; red[4 + (threadIdx.x >> 6)] = s2; }
    __syncthreads();
    float ts = red[0] + red[1] + red[2] + red[3];
    float t2 = red[4] + red[5] + red[6] + red[7];
    float mu = ts * (1.0f / CDIM);
    float var = t2 * (1.0f / CDIM) - mu * mu;
    float rstd = rsqrtf(var + 1e-5f);
    float a0 = (v0 - mu) * rstd * g[threadIdx.x] + b[threadIdx.x];
    float a1 = (v1 - mu) * rstd * g[threadIdx.x + 256] + b[threadIdx.x + 256];
    float a2v = (v2 - mu) * rstd * g[threadIdx.x + 512] + b[threadIdx.x + 512];
    float mx = fmaxf(fabsf(a0), fmaxf(fabsf(a1), fabsf(a2v)));
    for (int off = 32; off > 0; off >>= 1) mx = fmaxf(mx, __shfl_down(mx, off));
    if ((threadIdx.x & 63) == 0) redm[threadIdx.x >> 6] = mx;
    __syncthreads();
    float rmax = fmaxf(fmaxf(redm[0], redm[1]), fmaxf(redm[2], redm[3]));
    rmax = fmaxf(rmax, 1e-20f);
    float inv = 127.f / rmax;
    signed char* orow = out + (size_t)row * CDIM;
    orow[threadIdx.x]       = (signed char)__float2int_rn(a0 * inv);
    orow[threadIdx.x + 256] = (signed char)__float2int_rn(a1 * inv);
    orow[threadIdx.x + 512] = (signed char)__float2int_rn(a2v * inv);
    if (threadIdx.x == 0) rowscale[row] = rmax * (1.f / 127.f);
}

// ---------- i8 GEMM: acc[M,N] = A[M,K] @ B[N,K]^T, i32 accum ----------
// 128xBN tile, 4 waves, 16x16x64 i8 MFMA, BK=64 bytes, global_load_lds staging.
enum { EPI_SIGN = 0, EPI_RESID = 1, EPI_GELU = 2, EPI_QKV = 3 };
#define MSCALE_INV 16.0f    // gelu-out quant: q = round(ge*16), dequant acc * (1/16)

template<int EPI, int BN>
__global__ void __launch_bounds__(256) gemm_i8(
    const signed char* __restrict__ A, const signed char* __restrict__ B,
    int M, int N, int K,
    const float* __restrict__ alpha, const float* __restrict__ bias,
    const float* __restrict__ ls, const float* __restrict__ resid,
    const float* __restrict__ rowscale, float ascale,
    float* __restrict__ outF, signed char* __restrict__ outB,
    signed char* __restrict__ vtB)
{
    __shared__ signed char As[128][64];
    __shared__ signed char Bs[BN][64];
    const int tid = threadIdx.x, ln = tid & 63, w = tid >> 6;
    const int wm = w >> 1, wn = w & 1;
    constexpr int NF = BN / 32;   // n-frags per wave

    // XCD-chunked bijective swizzle (all grids divisible by 8)
    const int nwg = gridDim.x * gridDim.y;
    const int id = blockIdx.y * gridDim.x + blockIdx.x;
    const int nid = (id & 7) * (nwg >> 3) + (id >> 3);
    const int bxs = nid % gridDim.x, bys = nid / gridDim.x;
    const int bm = bys * 128, bn = bxs * BN;

    const i32x4 iz = {0, 0, 0, 0};
    i32x4 acc[4][NF];
#pragma unroll
    for (int m = 0; m < 4; m++)
#pragma unroll
        for (int n = 0; n < NF; n++) acc[m][n] = iz;

    const int srow = tid >> 2, scol = (tid & 3) * 16;

    for (int k0 = 0; k0 < K; k0 += 64) {
        __syncthreads();
        gload_lds16(A + (size_t)(bm + srow) * K + k0 + scol, &As[srow][scol]);
        gload_lds16(A + (size_t)(bm + 64 + srow) * K + k0 + scol, &As[64 + srow][scol]);
        gload_lds16(B + (size_t)(bn + srow) * K + k0 + scol, &Bs[srow][scol]);
        if constexpr (BN == 128)
            gload_lds16(B + (size_t)(bn + 64 + srow) * K + k0 + scol, &Bs[64 + srow][scol]);
        __syncthreads();
        i32x4 aF[4], bF[NF];
#pragma unroll
        for (int m = 0; m < 4; m++) aF[m] = *(const i32x4*)&As[wm * 64 + m * 16 + (ln & 15)][16 * (ln >> 4)];
#pragma unroll
        for (int n = 0; n < NF; n++) bF[n] = *(const i32x4*)&Bs[wn * (BN / 2) + n * 16 + (ln & 15)][16 * (ln >> 4)];
#pragma unroll
        for (int m = 0; m < 4; m++)
#pragma unroll
            for (int n = 0; n < NF; n++)
                acc[m][n] = __builtin_amdgcn_mfma_i32_16x16x64_i8(aF[m], bF[n], acc[m][n], 0, 0, 0);
    }

    const int r0 = bm + wm * 64, c0 = bn + wn * (BN / 2);
#pragma unroll
    for (int m = 0; m < 4; m++) {
#pragma unroll
        for (int n = 0; n < NF; n++) {
            int c = c0 + n * 16 + (ln & 15);
#pragma unroll
            for (int i = 0; i < 4; i++) {
                int r = r0 + m * 16 + (ln >> 4) * 4 + i;
                int v = acc[m][n][i];
                if (EPI == EPI_SIGN) {
                    outB[(size_t)r * N + c] = (v >= 0) ? 1 : -1;
                } else if (EPI == EPI_QKV) {
                    // Q,K -> qk[token][1536]; V -> vt[(bh*64+d)*1024 + token]
                    signed char sv = (v >= 0) ? 1 : -1;
                    if (c < 1536) {
                        outB[(size_t)r * 1536 + c] = sv;
                    } else {
                        int hh = (c - 1536) >> 6, dd = (c - 1536) & 63;
                        vtB[(((size_t)(r >> 10) * NHEAD + hh) * 64 + dd) * SEQL + (r & 1023)] = sv;
                    }
                } else if (EPI == EPI_RESID) {
                    float t = alpha[c] * ((float)v * ascale) + bias[c];
                    size_t idx = (size_t)r * N + c;
                    outF[idx] = resid[idx] + ls[c] * t;
                } else {  // EPI_GELU: per-row dequant, gelu, fixed-scale i8 quant
                    float t = alpha[c] * ((float)v * rowscale[r]) + bias[c];
                    float ge = 0.5f * t * (1.0f + erff(t * 0.70710678118654752f));
                    float qf = fminf(fmaxf(ge * MSCALE_INV, -127.f), 127.f);
                    outB[(size_t)r * N + c] = (signed char)__float2int_rn(qf);
                }
            }
        }
    }
}

// ---------- binary attention v2 (exact i8) ----------
// mask = (Q.K^T > 0); O = mask @ V; emit sign(O).
// Grid: 96 (b,h) x 8 q-blocks of 128 rows. 4 waves x 32 q-rows.
// Swapped QK^T (mfma(K,Q) -> S^T) so the P mask packs to ds_write_b32 in
// exactly the A-operand layout PV needs. V pre-transposed globally (vt).
__global__ void __launch_bounds__(256) attn_v2(const signed char* __restrict__ qk,
                                               const signed char* __restrict__ vt,
                                               signed char* __restrict__ a2) {
    // XCD swizzle: consecutive nid (same bh) on the same XCD -> K/V L2-local
    const int id = blockIdx.x;                       // 0..767
    const int nid = (id & 7) * 96 + (id >> 3);
    const int bh = nid >> 3, qb = nid & 7;
    const int b = bh / NHEAD, h = bh % NHEAD;
    const int tid = threadIdx.x, ln = tid & 63, w = tid >> 6;
    const int lq = ln & 15, khi = ln >> 4;

    __shared__ signed char Ks[64][80];    // K tile: rows=kv token, 80B pad (2-way banks)
    __shared__ signed char Vts[64][80];   // V^T tile: rows=d, cols=kv token
    __shared__ signed char Pw[4][32][80]; // per-wave P[q][m]

    const size_t tokbase = (size_t)b * SEQL;
    const int q0 = qb * 128 + w * 32;     // wave's q-row base (within sequence)
    const int str = tid >> 2, stc = (tid & 3) * 16;
    const size_t vtrow = ((size_t)bh * 64 + str) * SEQL;

    // hoist Q B-operand fragments (lane: row q0+qf*16+lq, bytes khi*16..)
    i32x4 qfrag[2];
#pragma unroll
    for (int qf = 0; qf < 2; qf++)
        qfrag[qf] = *(const i32x4*)(qk + (tokbase + q0 + qf * 16 + lq) * 1536 + h * 64 + khi * 16);

    const i32x4 iz = {0, 0, 0, 0};
    i32x4 o[2][4];
#pragma unroll
    for (int qf = 0; qf < 2; qf++)
#pragma unroll
        for (int df = 0; df < 4; df++) o[qf][df] = iz;

    auto LOADJ = [&](int j, sc16& kr, sc16& vr) {
        kr = *(const sc16*)(qk + (tokbase + j * 64 + str) * 1536 + 768 + h * 64 + stc);
        vr = *(const sc16*)(vt + vtrow + j * 64 + stc);
    };
    auto STORE = [&](const sc16& kr, const sc16& vr) {
        *(sc16*)&Ks[str][stc] = kr;
        *(sc16*)&Vts[str][stc] = vr;
    };
    auto COMPUTE = [&]() {
        // QK^T swapped: A = K (rows m), B = Q (rows q) -> S^T frags
        i32x4 kfrag[4];
#pragma unroll
        for (int kf = 0; kf < 4; kf++)
            kfrag[kf] = *(const i32x4*)&Ks[kf * 16 + lq][khi * 16];
#pragma unroll
        for (int kf = 0; kf < 4; kf++) {
#pragma unroll
            for (int qf = 0; qf < 2; qf++) {
                i32x4 st = __builtin_amdgcn_mfma_i32_16x16x64_i8(kfrag[kf], qfrag[qf], iz, 0, 0, 0);
                // st[i] = S^T[m = kf*16 + khi*4 + i][q = qf*16 + lq]
                unsigned pb = (st[0] > 0 ? 1u : 0u) | (st[1] > 0 ? 0x100u : 0u) |
                              (st[2] > 0 ? 0x10000u : 0u) | (st[3] > 0 ? 0x1000000u : 0u);
                *(unsigned*)&Pw[w][qf * 16 + lq][kf * 16 + khi * 4] = pb;
            }
        }
        // PV: A = P (rows q), B = V^T (rows d), k = m
        i32x4 pa[2];
#pragma unroll
        for (int qf = 0; qf < 2; qf++)
            pa[qf] = *(const i32x4*)&Pw[w][qf * 16 + lq][khi * 16];
#pragma unroll
        for (int df = 0; df < 4; df++) {
            i32x4 vfr = *(const i32x4*)&Vts[df * 16 + lq][khi * 16];
#pragma unroll
            for (int qf = 0; qf < 2; qf++)
                o[qf][df] = __builtin_amdgcn_mfma_i32_16x16x64_i8(pa[qf], vfr, o[qf][df], 0, 0, 0);
        }
    };

    sc16 ka, va, kb, vb;
    LOADJ(0, ka, va);
#pragma unroll 1
    for (int jj = 0; jj < 16; jj += 2) {
        __syncthreads();
        STORE(ka, va);
        __syncthreads();
        LOADJ(jj + 1, kb, vb);
        COMPUTE();
        __syncthreads();
        STORE(kb, vb);
        __syncthreads();
        if (jj + 2 < 16) LOADJ(jj + 2, ka, va);
        COMPUTE();
    }

    // epilogue: a2[token][h*64 + d] = sign(o)
#pragma unroll
    for (int qf = 0; qf < 2; qf++)
#pragma unroll
        for (int df = 0; df < 4; df++)
#pragma unroll
            for (int i = 0; i < 4; i++) {
                int qrow = q0 + qf * 16 + khi * 4 + i;
                int dim = df * 16 + lq;
                a2[(tokbase + qrow) * CDIM + h * 64 + dim] = (o[qf][df][i] >= 0) ? 1 : -1;
            }
}

// ---------- workspace layout (bytes) ----------
static const size_t OFF_WQKV  = 0;          // 2304*768   = 1769472
static const size_t OFF_WPROJ = 1769472;    // 768*768    = 589824
static const size_t OFF_WFC1  = 2359296;    // 3072*768   = 2359296
static const size_t OFF_WFC2  = 4718592;    // 768*3072   = 2359296
static const size_t OFF_APROJ = 7077888;    // 768*4
static const size_t OFF_AFC1  = 7080960;    // 3072*4
static const size_t OFF_AFC2  = 7093248;    // 768*4
static const size_t OFF_H2SC  = 7096320;    // 8192*4
static const size_t OFF_QK    = 7129088;    // 8192*1536  = 12582912
static const size_t OFF_VT    = 19712000;   // 96*64*1024 = 6291456
static const size_t OFF_A2    = 26003456;   // 8192*768   = 6291456
static const size_t OFF_A1    = 32294912;   // 8192*768   = 6291456
static const size_t OFF_M1    = 38586368;   // 8192*3072  = 25165824
static const size_t OFF_H2    = 63752192;   // 8192*768   = 6291456
// total = 70043648 bytes

extern "C" void kernel_launch(void* const* d_in, const int* in_sizes, int n_in,
                              void* d_out, int out_size, void* d_ws, size_t ws_size,
                              hipStream_t stream) {
    const float* x      = (const float*)d_in[0];
    const float* ln1_g  = (const float*)d_in[1];
    const float* ln1_b  = (const float*)d_in[2];
    const float* w_qkv  = (const float*)d_in[3];
    const float* w_proj = (const float*)d_in[4];
    const float* b_proj = (const float*)d_in[5];
    const float* ls1_g  = (const float*)d_in[6];
    const float* ln2_g  = (const float*)d_in[7];
    const float* ln2_b  = (const float*)d_in[8];
    const float* w_fc1  = (const float*)d_in[9];
    const float* b_fc1  = (const float*)d_in[10];
    const float* w_fc2  = (const float*)d_in[11];
    const float* b_fc2  = (const float*)d_in[12];
    const float* ls2_g  = (const float*)d_in[13];
    float* out = (float*)d_out;

    char* ws = (char*)d_ws;
    signed char* wqkv_s  = (signed char*)(ws + OFF_WQKV);
    signed char* wproj_s = (signed char*)(ws + OFF_WPROJ);
    signed char* wfc1_s  = (signed char*)(ws + OFF_WFC1);
    signed char* wfc2_s  = (signed char*)(ws + OFF_WFC2);
    float* a_proj  = (float*)(ws + OFF_APROJ);
    float* a_fc1   = (float*)(ws + OFF_AFC1);
    float* a_fc2   = (float*)(ws + OFF_AFC2);
    float* h2scale = (float*)(ws + OFF_H2SC);
    signed char* qk   = (signed char*)(ws + OFF_QK);
    signed char* vt   = (signed char*)(ws + OFF_VT);
    signed char* a2   = (signed char*)(ws + OFF_A2);
    signed char* a1   = (signed char*)(ws + OFF_A1);
    signed char* m1   = (signed char*)(ws + OFF_M1);
    signed char* h2   = (signed char*)(ws + OFF_H2);

    // weight prep
    sign_w_kernel<<<512, 256, 0, stream>>>(w_qkv, wqkv_s, NQKV * CDIM);
    signalpha_kernel<<<CDIM, 256, 0, stream>>>(w_proj, wproj_s, a_proj, CDIM);
    signalpha_kernel<<<HIDD, 256, 0, stream>>>(w_fc1,  wfc1_s,  a_fc1,  CDIM);
    signalpha_kernel<<<CDIM, 256, 0, stream>>>(w_fc2,  wfc2_s,  a_fc2,  HIDD);

    // LN1 + sign
    ln_sign_kernel<<<NTOK, 256, 0, stream>>>(x, ln1_g, ln1_b, a1);

    // QKV: sign(a1 @ wqkv^T); Q,K -> qk[8192][1536], V -> vt transposed
    gemm_i8<EPI_QKV, 128><<<dim3(NQKV / 128, NTOK / 128), 256, 0, stream>>>(
        a1, wqkv_s, NTOK, NQKV, CDIM, nullptr, nullptr, nullptr, nullptr, nullptr, 1.0f, nullptr, qk, vt);

    // binary attention -> sign(O) (exact i8)
    attn_v2<<<768, 256, 0, stream>>>(qk, vt, a2);

    // proj + layerscale residual: out(x1) = x + ls1*(alpha_proj*acc + b_proj)   (acc exact)
    gemm_i8<EPI_RESID, 64><<<dim3(CDIM / 64, NTOK / 128), 256, 0, stream>>>(
        a2, wproj_s, NTOK, CDIM, CDIM, a_proj, b_proj, ls1_g, x, nullptr, 1.0f, out, nullptr, nullptr);

    // LN2 + per-row i8 quant (reads x1 from d_out)
    ln2q_kernel<<<NTOK, 256, 0, stream>>>(out, ln2_g, ln2_b, h2, h2scale);

    // fc1 + gelu -> fixed-scale i8
    gemm_i8<EPI_GELU, 128><<<dim3(HIDD / 128, NTOK / 128), 256, 0, stream>>>(
        h2, wfc1_s, NTOK, HIDD, CDIM, a_fc1, b_fc1, nullptr, nullptr, h2scale, 1.0f, nullptr, m1, nullptr);

    // fc2 + layerscale residual (in-place on d_out); dequant by 1/16
    gemm_i8<EPI_RESID, 64><<<dim3(CDIM / 64, NTOK / 128), 256, 0, stream>>>(
        m1, wfc2_s, NTOK, CDIM, HIDD, a_fc2, b_fc2, ls2_g, out, nullptr, 1.0f / MSCALE_INV, out, nullptr, nullptr);
}

// Round 5
// 187.647 us; speedup vs baseline: 1.8778x; 1.1161x over previous
//
#include <hip/hip_runtime.h>

// ---- problem constants ----
#define NTOK 8192      // B*N = 8*1024
#define CDIM 768
#define HIDD 3072
#define NQKV 2304
#define SEQL 1024
#define NHEAD 12

typedef int i32x4 __attribute__((ext_vector_type(4)));
typedef signed char sc16 __attribute__((ext_vector_type(16)));

// async global->LDS, 16B per lane. Dest must be wave-uniform base + lane*16.
__device__ __forceinline__ void gload_lds16(const void* g, void* l) {
    __builtin_amdgcn_global_load_lds(
        (const __attribute__((address_space(1))) unsigned int*)g,
        (__attribute__((address_space(3))) unsigned int*)l, 16, 0, 0);
}

// sign(w) as i8 +-1 (x>=0 -> +1 per ste_sign)
__global__ void sign_w_kernel(const float* __restrict__ w, signed char* __restrict__ ws, int n) {
    int i = blockIdx.x * blockDim.x + threadIdx.x;
    int stride = gridDim.x * blockDim.x;
    for (; i < n; i += stride)
        ws[i] = (w[i] >= 0.0f) ? 1 : -1;
}

// fused: sign(w) i8 + alpha[row] = mean|w[row,:]|
__global__ void __launch_bounds__(256) signalpha_kernel(const float* __restrict__ w,
                                                        signed char* __restrict__ ws,
                                                        float* __restrict__ alpha, int K) {
    int row = blockIdx.x;
    const float* wr = w + (size_t)row * K;
    signed char* wsr = ws + (size_t)row * K;
    float s = 0.f;
    for (int i = threadIdx.x; i < K; i += 256) {
        float v = wr[i];
        wsr[i] = (v >= 0.f) ? 1 : -1;
        s += fabsf(v);
    }
    for (int off = 32; off > 0; off >>= 1) s += __shfl_down(s, off);
    __shared__ float red[4];
    if ((threadIdx.x & 63) == 0) red[threadIdx.x >> 6] = s;
    __syncthreads();
    if (threadIdx.x == 0) alpha[row] = (red[0] + red[1] + red[2] + red[3]) / (float)K;
}

// LayerNorm over 768 -> sign as i8 +-1 (for LN1 path)
__global__ void __launch_bounds__(256) ln_sign_kernel(const float* __restrict__ x, const float* __restrict__ g,
                                                      const float* __restrict__ b, signed char* __restrict__ out) {
    int row = blockIdx.x;
    const float* xr = x + (size_t)row * CDIM;
    float v0 = xr[threadIdx.x], v1 = xr[threadIdx.x + 256], v2 = xr[threadIdx.x + 512];
    float s = v0 + v1 + v2, s2 = v0 * v0 + v1 * v1 + v2 * v2;
    for (int off = 32; off > 0; off >>= 1) { s += __shfl_down(s, off); s2 += __shfl_down(s2, off); }
    __shared__ float red[8];
    if ((threadIdx.x & 63) == 0) { red[threadIdx.x >> 6] = s; red[4 + (threadIdx.x >> 6)] = s2; }
    __syncthreads();
    float ts = red[0] + red[1] + red[2] + red[3];
    float t2 = red[4] + red[5] + red[6] + red[7];
    float mu = ts * (1.0f / CDIM);
    float var = t2 * (1.0f / CDIM) - mu * mu;
    float rstd = rsqrtf(var + 1e-5f);
    signed char* orow = out + (size_t)row * CDIM;
    float vv[3] = {v0, v1, v2};
#pragma unroll
    for (int p = 0; p < 3; p++) {
        int i = threadIdx.x + p * 256;
        float val = (vv[p] - mu) * rstd * g[i] + b[i];
        orow[i] = (val >= 0.f) ? 1 : -1;
    }
}

// LayerNorm over 768 -> per-row i8 quant (for LN2/fc1 path); rowscale[row] = rowmax/127
__global__ void __launch_bounds__(256) ln2q_kernel(const float* __restrict__ x, const float* __restrict__ g,
                                                   const float* __restrict__ b, signed char* __restrict__ out,
                                                   float* __restrict__ rowscale) {
    int row = blockIdx.x;
    const float* xr = x + (size_t)row * CDIM;
    float v0 = xr[threadIdx.x], v1 = xr[threadIdx.x + 256], v2 = xr[threadIdx.x + 512];
    float s = v0 + v1 + v2, s2 = v0 * v0 + v1 * v1 + v2 * v2;
    for (int off = 32; off > 0; off >>= 1) { s += __shfl_down(s, off); s2 += __shfl_down(s2, off); }
    __shared__ float red[8];
    __shared__ float redm[4];
    if ((threadIdx.x & 63) == 0) { red[threadIdx.x >> 6] = s; red[4 + (threadIdx.x >> 6)] = s2; }
    __syncthreads();
    float ts = red[0] + red[1] + red[2] + red[3];
    float t2 = red[4] + red[5] + red[6] + red[7];
    float mu = ts * (1.0f / CDIM);
    float var = t2 * (1.0f / CDIM) - mu * mu;
    float rstd = rsqrtf(var + 1e-5f);
    float a0 = (v0 - mu) * rstd * g[threadIdx.x] + b[threadIdx.x];
    float a1 = (v1 - mu) * rstd * g[threadIdx.x + 256] + b[threadIdx.x + 256];
    float a2v = (v2 - mu) * rstd * g[threadIdx.x + 512] + b[threadIdx.x + 512];
    float mx = fmaxf(fabsf(a0), fmaxf(fabsf(a1), fabsf(a2v)));
    for (int off = 32; off > 0; off >>= 1) mx = fmaxf(mx, __shfl_down(mx, off));
    if ((threadIdx.x & 63) == 0) redm[threadIdx.x >> 6] = mx;
    __syncthreads();
    float rmax = fmaxf(fmaxf(redm[0], redm[1]), fmaxf(redm[2], redm[3]));
    rmax = fmaxf(rmax, 1e-20f);
    float inv = 127.f / rmax;
    signed char* orow = out + (size_t)row * CDIM;
    orow[threadIdx.x]       = (signed char)__float2int_rn(a0 * inv);
    orow[threadIdx.x + 256] = (signed char)__float2int_rn(a1 * inv);
    orow[threadIdx.x + 512] = (signed char)__float2int_rn(a2v * inv);
    if (threadIdx.x == 0) rowscale[row] = rmax * (1.f / 127.f);
}

// ---------- i8 GEMM: acc[M,N] = A[M,K] @ B[N,K]^T, i32 accum ----------
// 128xBN tile, 4 waves, 16x16x64 i8 MFMA, BK=64 bytes.
// Double-buffered LDS, ONE barrier per K-step (loads for t+1 issued right after
// the barrier, drained at the next barrier -> hidden under ds_read+MFMA of t).
// XOR slot-swizzle (slot ^ (row>>1)&3) on global source + LDS read: ds_read_b128
// conflict-free while keeping the gload_lds dest linear.
enum { EPI_SIGN = 0, EPI_RESID = 1, EPI_GELU = 2, EPI_QKV = 3 };
#define MSCALE_INV 16.0f    // gelu-out quant: q = round(ge*16), dequant acc * (1/16)

template<int EPI, int BN>
__global__ void __launch_bounds__(256) gemm_i8(
    const signed char* __restrict__ A, const signed char* __restrict__ B,
    int M, int N, int K,
    const float* __restrict__ alpha, const float* __restrict__ bias,
    const float* __restrict__ ls, const float* __restrict__ resid,
    const float* __restrict__ rowscale, float ascale,
    float* __restrict__ outF, signed char* __restrict__ outB,
    signed char* __restrict__ vtB)
{
    __shared__ signed char As[2][128][64];
    __shared__ signed char Bs[2][BN][64];
    const int tid = threadIdx.x, ln = tid & 63, w = tid >> 6;
    const int wm = w >> 1, wn = w & 1;
    const int lq = ln & 15, khi = ln >> 4;
    constexpr int NF = BN / 32;   // n-frags per wave

    // XCD-chunked bijective swizzle (all grids divisible by 8)
    const int nwg = gridDim.x * gridDim.y;
    const int id = blockIdx.y * gridDim.x + blockIdx.x;
    const int nid = (id & 7) * (nwg >> 3) + (id >> 3);
    const int bxs = nid % gridDim.x, bys = nid / gridDim.x;
    const int bm = bys * 128, bn = bxs * BN;

    const i32x4 iz = {0, 0, 0, 0};
    i32x4 acc[4][NF];
#pragma unroll
    for (int m = 0; m < 4; m++)
#pragma unroll
        for (int n = 0; n < NF; n++) acc[m][n] = iz;

    const int srow = tid >> 2, scol = (tid & 3) * 16;
    const int ssrc = ((tid & 3) ^ ((srow >> 1) & 3)) * 16;   // pre-swizzled global slot
    const int sa = 16 * (khi ^ ((lq >> 1) & 3));             // swizzled LDS read slot

    auto STAGE = [&](int p, int k0) {
        gload_lds16(A + (size_t)(bm + srow) * K + k0 + ssrc, &As[p][srow][scol]);
        gload_lds16(A + (size_t)(bm + 64 + srow) * K + k0 + ssrc, &As[p][64 + srow][scol]);
        gload_lds16(B + (size_t)(bn + srow) * K + k0 + ssrc, &Bs[p][srow][scol]);
        if constexpr (BN == 128)
            gload_lds16(B + (size_t)(bn + 64 + srow) * K + k0 + ssrc, &Bs[p][64 + srow][scol]);
    };

    STAGE(0, 0);
    const int nst = K >> 6;
#pragma unroll 1
    for (int t = 0; t < nst; t++) {
        const int p = t & 1;
        __syncthreads();                       // buf[p] ready (vmcnt drained here)
        if (t + 1 < nst) STAGE(p ^ 1, (t + 1) << 6);   // overlaps with compute below
        i32x4 aF[4], bF[NF];
#pragma unroll
        for (int m = 0; m < 4; m++) aF[m] = *(const i32x4*)&As[p][wm * 64 + m * 16 + lq][sa];
#pragma unroll
        for (int n = 0; n < NF; n++) bF[n] = *(const i32x4*)&Bs[p][wn * (BN / 2) + n * 16 + lq][sa];
#pragma unroll
        for (int m = 0; m < 4; m++)
#pragma unroll
            for (int n = 0; n < NF; n++)
                acc[m][n] = __builtin_amdgcn_mfma_i32_16x16x64_i8(aF[m], bF[n], acc[m][n], 0, 0, 0);
    }

    const int r0 = bm + wm * 64, c0 = bn + wn * (BN / 2);
#pragma unroll
    for (int m = 0; m < 4; m++) {
#pragma unroll
        for (int n = 0; n < NF; n++) {
            int c = c0 + n * 16 + lq;
#pragma unroll
            for (int i = 0; i < 4; i++) {
                int r = r0 + m * 16 + khi * 4 + i;
                int v = acc[m][n][i];
                if (EPI == EPI_SIGN) {
                    outB[(size_t)r * N + c] = (v >= 0) ? 1 : -1;
                } else if (EPI == EPI_RESID) {
                    float t = alpha[c] * ((float)v * ascale) + bias[c];
                    size_t idx = (size_t)r * N + c;
                    outF[idx] = resid[idx] + ls[c] * t;
                } else if (EPI == EPI_GELU) {  // per-row dequant, gelu, fixed-scale i8 quant
                    float t = alpha[c] * ((float)v * rowscale[r]) + bias[c];
                    float ge = 0.5f * t * (1.0f + erff(t * 0.70710678118654752f));
                    float qf = fminf(fmaxf(ge * MSCALE_INV, -127.f), 127.f);
                    outB[(size_t)r * N + c] = (signed char)__float2int_rn(qf);
                }
            }
            if (EPI == EPI_QKV) {
                // Q,K -> qk[token][1536]; V -> vt[(bh*64+d)*1024 + token] (u32-packed)
                if (c < 1536) {
#pragma unroll
                    for (int i = 0; i < 4; i++) {
                        int r = r0 + m * 16 + khi * 4 + i;
                        outB[(size_t)r * 1536 + c] = (acc[m][n][i] >= 0) ? 1 : -1;
                    }
                } else {
                    int rb = r0 + m * 16 + khi * 4;            // multiple of 4
                    int hh = (c - 1536) >> 6, dd = (c - 1536) & 63;
                    unsigned pk = 0;
#pragma unroll
                    for (int i = 0; i < 4; i++)
                        pk |= (unsigned)(unsigned char)((acc[m][n][i] >= 0) ? 1 : -1) << (8 * i);
                    *(unsigned*)(vtB + (((size_t)(rb >> 10) * NHEAD + hh) * 64 + dd) * SEQL + (rb & 1023)) = pk;
                }
            }
        }
    }
}

// ---------- binary attention v2 (exact i8) ----------
// mask = (Q.K^T > 0); O = mask @ V; emit sign(O).
// Grid: 96 (b,h) x 8 q-blocks of 128 rows. 4 waves x 32 q-rows.
__global__ void __launch_bounds__(256) attn_v2(const signed char* __restrict__ qk,
                                               const signed char* __restrict__ vt,
                                               signed char* __restrict__ a2) {
    const int id = blockIdx.x;                       // 0..767
    const int nid = (id & 7) * 96 + (id >> 3);
    const int bh = nid >> 3, qb = nid & 7;
    const int b = bh / NHEAD, h = bh % NHEAD;
    const int tid = threadIdx.x, ln = tid & 63, w = tid >> 6;
    const int lq = ln & 15, khi = ln >> 4;

    __shared__ signed char Ks[64][80];    // K tile: rows=kv token, 80B pad
    __shared__ signed char Vts[64][80];   // V^T tile: rows=d, cols=kv token
    __shared__ signed char Pw[4][32][80]; // per-wave P[q][m]

    const size_t tokbase = (size_t)b * SEQL;
    const int q0 = qb * 128 + w * 32;
    const int str = tid >> 2, stc = (tid & 3) * 16;
    const size_t vtrow = ((size_t)bh * 64 + str) * SEQL;

    i32x4 qfrag[2];
#pragma unroll
    for (int qf = 0; qf < 2; qf++)
        qfrag[qf] = *(const i32x4*)(qk + (tokbase + q0 + qf * 16 + lq) * 1536 + h * 64 + khi * 16);

    const i32x4 iz = {0, 0, 0, 0};
    i32x4 o[2][4];
#pragma unroll
    for (int qf = 0; qf < 2; qf++)
#pragma unroll
        for (int df = 0; df < 4; df++) o[qf][df] = iz;

    auto LOADJ = [&](int j, sc16& kr, sc16& vr) {
        kr = *(const sc16*)(qk + (tokbase + j * 64 + str) * 1536 + 768 + h * 64 + stc);
        vr = *(const sc16*)(vt + vtrow + j * 64 + stc);
    };
    auto STORE = [&](const sc16& kr, const sc16& vr) {
        *(sc16*)&Ks[str][stc] = kr;
        *(sc16*)&Vts[str][stc] = vr;
    };
    auto COMPUTE = [&]() {
        i32x4 kfrag[4];
#pragma unroll
        for (int kf = 0; kf < 4; kf++)
            kfrag[kf] = *(const i32x4*)&Ks[kf * 16 + lq][khi * 16];
#pragma unroll
        for (int kf = 0; kf < 4; kf++) {
#pragma unroll
            for (int qf = 0; qf < 2; qf++) {
                i32x4 st = __builtin_amdgcn_mfma_i32_16x16x64_i8(kfrag[kf], qfrag[qf], iz, 0, 0, 0);
                unsigned pb = (st[0] > 0 ? 1u : 0u) | (st[1] > 0 ? 0x100u : 0u) |
                              (st[2] > 0 ? 0x10000u : 0u) | (st[3] > 0 ? 0x1000000u : 0u);
                *(unsigned*)&Pw[w][qf * 16 + lq][kf * 16 + khi * 4] = pb;
            }
        }
        i32x4 pa[2];
#pragma unroll
        for (int qf = 0; qf < 2; qf++)
            pa[qf] = *(const i32x4*)&Pw[w][qf * 16 + lq][khi * 16];
#pragma unroll
        for (int df = 0; df < 4; df++) {
            i32x4 vfr = *(const i32x4*)&Vts[df * 16 + lq][khi * 16];
#pragma unroll
            for (int qf = 0; qf < 2; qf++)
                o[qf][df] = __builtin_amdgcn_mfma_i32_16x16x64_i8(pa[qf], vfr, o[qf][df], 0, 0, 0);
        }
    };

    sc16 ka, va, kb, vb;
    LOADJ(0, ka, va);
#pragma unroll 1
    for (int jj = 0; jj < 16; jj += 2) {
        __syncthreads();
        STORE(ka, va);
        __syncthreads();
        LOADJ(jj + 1, kb, vb);
        COMPUTE();
        __syncthreads();
        STORE(kb, vb);
        __syncthreads();
        if (jj + 2 < 16) LOADJ(jj + 2, ka, va);
        COMPUTE();
    }

#pragma unroll
    for (int qf = 0; qf < 2; qf++)
#pragma unroll
        for (int df = 0; df < 4; df++)
#pragma unroll
            for (int i = 0; i < 4; i++) {
                int qrow = q0 + qf * 16 + khi * 4 + i;
                int dim = df * 16 + lq;
                a2[(tokbase + qrow) * CDIM + h * 64 + dim] = (o[qf][df][i] >= 0) ? 1 : -1;
            }
}

// ---------- workspace layout (bytes) ----------
static const size_t OFF_WQKV  = 0;          // 2304*768   = 1769472
static const size_t OFF_WPROJ = 1769472;    // 768*768    = 589824
static const size_t OFF_WFC1  = 2359296;    // 3072*768   = 2359296
static const size_t OFF_WFC2  = 4718592;    // 768*3072   = 2359296
static const size_t OFF_APROJ = 7077888;    // 768*4
static const size_t OFF_AFC1  = 7080960;    // 3072*4
static const size_t OFF_AFC2  = 7093248;    // 768*4
static const size_t OFF_H2SC  = 7096320;    // 8192*4
static const size_t OFF_QK    = 7129088;    // 8192*1536  = 12582912
static const size_t OFF_VT    = 19712000;   // 96*64*1024 = 6291456
static const size_t OFF_A2    = 26003456;   // 8192*768   = 6291456
static const size_t OFF_A1    = 32294912;   // 8192*768   = 6291456
static const size_t OFF_M1    = 38586368;   // 8192*3072  = 25165824
static const size_t OFF_H2    = 63752192;   // 8192*768   = 6291456
// total = 70043648 bytes

extern "C" void kernel_launch(void* const* d_in, const int* in_sizes, int n_in,
                              void* d_out, int out_size, void* d_ws, size_t ws_size,
                              hipStream_t stream) {
    const float* x      = (const float*)d_in[0];
    const float* ln1_g  = (const float*)d_in[1];
    const float* ln1_b  = (const float*)d_in[2];
    const float* w_qkv  = (const float*)d_in[3];
    const float* w_proj = (const float*)d_in[4];
    const float* b_proj = (const float*)d_in[5];
    const float* ls1_g  = (const float*)d_in[6];
    const float* ln2_g  = (const float*)d_in[7];
    const float* ln2_b  = (const float*)d_in[8];
    const float* w_fc1  = (const float*)d_in[9];
    const float* b_fc1  = (const float*)d_in[10];
    const float* w_fc2  = (const float*)d_in[11];
    const float* b_fc2  = (const float*)d_in[12];
    const float* ls2_g  = (const float*)d_in[13];
    float* out = (float*)d_out;

    char* ws = (char*)d_ws;
    signed char* wqkv_s  = (signed char*)(ws + OFF_WQKV);
    signed char* wproj_s = (signed char*)(ws + OFF_WPROJ);
    signed char* wfc1_s  = (signed char*)(ws + OFF_WFC1);
    signed char* wfc2_s  = (signed char*)(ws + OFF_WFC2);
    float* a_proj  = (float*)(ws + OFF_APROJ);
    float* a_fc1   = (float*)(ws + OFF_AFC1);
    float* a_fc2   = (float*)(ws + OFF_AFC2);
    float* h2scale = (float*)(ws + OFF_H2SC);
    signed char* qk   = (signed char*)(ws + OFF_QK);
    signed char* vt   = (signed char*)(ws + OFF_VT);
    signed char* a2   = (signed char*)(ws + OFF_A2);
    signed char* a1   = (signed char*)(ws + OFF_A1);
    signed char* m1   = (signed char*)(ws + OFF_M1);
    signed char* h2   = (signed char*)(ws + OFF_H2);

    // weight prep
    sign_w_kernel<<<512, 256, 0, stream>>>(w_qkv, wqkv_s, NQKV * CDIM);
    signalpha_kernel<<<CDIM, 256, 0, stream>>>(w_proj, wproj_s, a_proj, CDIM);
    signalpha_kernel<<<HIDD, 256, 0, stream>>>(w_fc1,  wfc1_s,  a_fc1,  CDIM);
    signalpha_kernel<<<CDIM, 256, 0, stream>>>(w_fc2,  wfc2_s,  a_fc2,  HIDD);

    // LN1 + sign
    ln_sign_kernel<<<NTOK, 256, 0, stream>>>(x, ln1_g, ln1_b, a1);

    // QKV: sign(a1 @ wqkv^T); Q,K -> qk[8192][1536], V -> vt transposed
    gemm_i8<EPI_QKV, 128><<<dim3(NQKV / 128, NTOK / 128), 256, 0, stream>>>(
        a1, wqkv_s, NTOK, NQKV, CDIM, nullptr, nullptr, nullptr, nullptr, nullptr, 1.0f, nullptr, qk, vt);

    // binary attention -> sign(O) (exact i8)
    attn_v2<<<768, 256, 0, stream>>>(qk, vt, a2);

    // proj + layerscale residual: out(x1) = x + ls1*(alpha_proj*acc + b_proj)
    gemm_i8<EPI_RESID, 64><<<dim3(CDIM / 64, NTOK / 128), 256, 0, stream>>>(
        a2, wproj_s, NTOK, CDIM, CDIM, a_proj, b_proj, ls1_g, x, nullptr, 1.0f, out, nullptr, nullptr);

    // LN2 + per-row i8 quant (reads x1 from d_out)
    ln2q_kernel<<<NTOK, 256, 0, stream>>>(out, ln2_g, ln2_b, h2, h2scale);

    // fc1 + gelu -> fixed-scale i8
    gemm_i8<EPI_GELU, 128><<<dim3(HIDD / 128, NTOK / 128), 256, 0, stream>>>(
        h2, wfc1_s, NTOK, HIDD, CDIM, a_fc1, b_fc1, nullptr, nullptr, h2scale, 1.0f, nullptr, m1, nullptr);

    // fc2 + layerscale residual (in-place on d_out); dequant by 1/16
    gemm_i8<EPI_RESID, 64><<<dim3(CDIM / 64, NTOK / 128), 256, 0, stream>>>(
        m1, wfc2_s, NTOK, CDIM, HIDD, a_fc2, b_fc2, ls2_g, out, nullptr, 1.0f / MSCALE_INV, out, nullptr, nullptr);
}

// Round 6
// 178.392 us; speedup vs baseline: 1.9753x; 1.0519x over previous
//
#include <hip/hip_runtime.h>

// ---- problem constants ----
#define NTOK 8192      // B*N = 8*1024
#define CDIM 768
#define HIDD 3072
#define NQKV 2304
#define SEQL 1024
#define NHEAD 12

typedef int i32x4 __attribute__((ext_vector_type(4)));
typedef signed char sc16 __attribute__((ext_vector_type(16)));

// async global->LDS, 16B per lane. Dest must be wave-uniform base + lane*16.
__device__ __forceinline__ void gload_lds16(const void* g, void* l) {
    __builtin_amdgcn_global_load_lds(
        (const __attribute__((address_space(1))) unsigned int*)g,
        (__attribute__((address_space(3))) unsigned int*)l, 16, 0, 0);
}

// sign(w) as i8 +-1 (x>=0 -> +1 per ste_sign)
__global__ void sign_w_kernel(const float* __restrict__ w, signed char* __restrict__ ws, int n) {
    int i = blockIdx.x * blockDim.x + threadIdx.x;
    int stride = gridDim.x * blockDim.x;
    for (; i < n; i += stride)
        ws[i] = (w[i] >= 0.0f) ? 1 : -1;
}

// fused: sign(w) i8 + alpha[row] = mean|w[row,:]|
__global__ void __launch_bounds__(256) signalpha_kernel(const float* __restrict__ w,
                                                        signed char* __restrict__ ws,
                                                        float* __restrict__ alpha, int K) {
    int row = blockIdx.x;
    const float* wr = w + (size_t)row * K;
    signed char* wsr = ws + (size_t)row * K;
    float s = 0.f;
    for (int i = threadIdx.x; i < K; i += 256) {
        float v = wr[i];
        wsr[i] = (v >= 0.f) ? 1 : -1;
        s += fabsf(v);
    }
    for (int off = 32; off > 0; off >>= 1) s += __shfl_down(s, off);
    __shared__ float red[4];
    if ((threadIdx.x & 63) == 0) red[threadIdx.x >> 6] = s;
    __syncthreads();
    if (threadIdx.x == 0) alpha[row] = (red[0] + red[1] + red[2] + red[3]) / (float)K;
}

// LayerNorm over 768 -> sign as i8 +-1 (for LN1 path)
__global__ void __launch_bounds__(256) ln_sign_kernel(const float* __restrict__ x, const float* __restrict__ g,
                                                      const float* __restrict__ b, signed char* __restrict__ out) {
    int row = blockIdx.x;
    const float* xr = x + (size_t)row * CDIM;
    float v0 = xr[threadIdx.x], v1 = xr[threadIdx.x + 256], v2 = xr[threadIdx.x + 512];
    float s = v0 + v1 + v2, s2 = v0 * v0 + v1 * v1 + v2 * v2;
    for (int off = 32; off > 0; off >>= 1) { s += __shfl_down(s, off); s2 += __shfl_down(s2, off); }
    __shared__ float red[8];
    if ((threadIdx.x & 63) == 0) { red[threadIdx.x >> 6] = s; red[4 + (threadIdx.x >> 6)] = s2; }
    __syncthreads();
    float ts = red[0] + red[1] + red[2] + red[3];
    float t2 = red[4] + red[5] + red[6] + red[7];
    float mu = ts * (1.0f / CDIM);
    float var = t2 * (1.0f / CDIM) - mu * mu;
    float rstd = rsqrtf(var + 1e-5f);
    signed char* orow = out + (size_t)row * CDIM;
    float vv[3] = {v0, v1, v2};
#pragma unroll
    for (int p = 0; p < 3; p++) {
        int i = threadIdx.x + p * 256;
        float val = (vv[p] - mu) * rstd * g[i] + b[i];
        orow[i] = (val >= 0.f) ? 1 : -1;
    }
}

// LayerNorm over 768 -> per-row i8 quant (for LN2/fc1 path); rowscale[row] = rowmax/127
__global__ void __launch_bounds__(256) ln2q_kernel(const float* __restrict__ x, const float* __restrict__ g,
                                                   const float* __restrict__ b, signed char* __restrict__ out,
                                                   float* __restrict__ rowscale) {
    int row = blockIdx.x;
    const float* xr = x + (size_t)row * CDIM;
    float v0 = xr[threadIdx.x], v1 = xr[threadIdx.x + 256], v2 = xr[threadIdx.x + 512];
    float s = v0 + v1 + v2, s2 = v0 * v0 + v1 * v1 + v2 * v2;
    for (int off = 32; off > 0; off >>= 1) { s += __shfl_down(s, off); s2 += __shfl_down(s2, off); }
    __shared__ float red[8];
    __shared__ float redm[4];
    if ((threadIdx.x & 63) == 0) { red[threadIdx.x >> 6] = s; red[4 + (threadIdx.x >> 6)] = s2; }
    __syncthreads();
    float ts = red[0] + red[1] + red[2] + red[3];
    float t2 = red[4] + red[5] + red[6] + red[7];
    float mu = ts * (1.0f / CDIM);
    float var = t2 * (1.0f / CDIM) - mu * mu;
    float rstd = rsqrtf(var + 1e-5f);
    float a0 = (v0 - mu) * rstd * g[threadIdx.x] + b[threadIdx.x];
    float a1 = (v1 - mu) * rstd * g[threadIdx.x + 256] + b[threadIdx.x + 256];
    float a2v = (v2 - mu) * rstd * g[threadIdx.x + 512] + b[threadIdx.x + 512];
    float mx = fmaxf(fabsf(a0), fmaxf(fabsf(a1), fabsf(a2v)));
    for (int off = 32; off > 0; off >>= 1) mx = fmaxf(mx, __shfl_down(mx, off));
    if ((threadIdx.x & 63) == 0) redm[threadIdx.x >> 6] = mx;
    __syncthreads();
    float rmax = fmaxf(fmaxf(redm[0], redm[1]), fmaxf(redm[2], redm[3]));
    rmax = fmaxf(rmax, 1e-20f);
    float inv = 127.f / rmax;
    signed char* orow = out + (size_t)row * CDIM;
    orow[threadIdx.x]       = (signed char)__float2int_rn(a0 * inv);
    orow[threadIdx.x + 256] = (signed char)__float2int_rn(a1 * inv);
    orow[threadIdx.x + 512] = (signed char)__float2int_rn(a2v * inv);
    if (threadIdx.x == 0) rowscale[row] = rmax * (1.f / 127.f);
}

// ---------- i8 GEMM: acc[M,N] = A[M,K] @ B[N,K]^T, i32 accum ----------
// 128xBN tile, 4 waves, 16x16x64 i8 MFMA, BK=64 bytes.
// 3-buffer LDS pipeline, counted vmcnt (T3+T4): stages issued 2 iterations
// ahead; per iteration: s_waitcnt vmcnt(L) + raw s_barrier (never drain to 0
// in steady state). XOR slot-swizzle keeps ds_read_b128 conflict-free with a
// linear gload_lds dest.
enum { EPI_SIGN = 0, EPI_RESID = 1, EPI_GELU = 2, EPI_QKV = 3 };
#define MSCALE_INV 16.0f    // gelu-out quant: q = round(ge*16), dequant acc * (1/16)

template<int EPI, int BN>
__global__ void __launch_bounds__(256) gemm_i8(
    const signed char* __restrict__ A, const signed char* __restrict__ B,
    int M, int N, int K,
    const float* __restrict__ alpha, const float* __restrict__ bias,
    const float* __restrict__ ls, const float* __restrict__ resid,
    const float* __restrict__ rowscale, float ascale,
    float* __restrict__ outF, signed char* __restrict__ outB,
    signed char* __restrict__ vtB)
{
    __shared__ signed char As[3][128][64];
    __shared__ signed char Bs[3][BN][64];
    const int tid = threadIdx.x, ln = tid & 63, w = tid >> 6;
    const int wm = w >> 1, wn = w & 1;
    const int lq = ln & 15, khi = ln >> 4;
    constexpr int NF = BN / 32;                  // n-frags per wave
    constexpr int L = (BN == 128) ? 4 : 3;       // gload_lds per stage per thread

    // XCD-chunked bijective swizzle (all grids divisible by 8)
    const int nwg = gridDim.x * gridDim.y;
    const int id = blockIdx.y * gridDim.x + blockIdx.x;
    const int nid = (id & 7) * (nwg >> 3) + (id >> 3);
    const int bxs = nid % gridDim.x, bys = nid / gridDim.x;
    const int bm = bys * 128, bn = bxs * BN;

    const i32x4 iz = {0, 0, 0, 0};
    i32x4 acc[4][NF];
#pragma unroll
    for (int m = 0; m < 4; m++)
#pragma unroll
        for (int n = 0; n < NF; n++) acc[m][n] = iz;

    const int srow = tid >> 2, scol = (tid & 3) * 16;
    const int ssrc = ((tid & 3) ^ ((srow >> 1) & 3)) * 16;   // pre-swizzled global slot
    const int sa = 16 * (khi ^ ((lq >> 1) & 3));             // swizzled LDS read slot

    auto STAGE = [&](int p, int k0) {
        gload_lds16(A + (size_t)(bm + srow) * K + k0 + ssrc, &As[p][srow][scol]);
        gload_lds16(A + (size_t)(bm + 64 + srow) * K + k0 + ssrc, &As[p][64 + srow][scol]);
        gload_lds16(B + (size_t)(bn + srow) * K + k0 + ssrc, &Bs[p][srow][scol]);
        if constexpr (BN == 128)
            gload_lds16(B + (size_t)(bn + 64 + srow) * K + k0 + ssrc, &Bs[p][64 + srow][scol]);
    };
    auto COMPUTE = [&](int p, bool prefetch, int knext) {
        i32x4 aF[4], bF[NF];
#pragma unroll
        for (int m = 0; m < 4; m++) aF[m] = *(const i32x4*)&As[p][wm * 64 + m * 16 + lq][sa];
#pragma unroll
        for (int n = 0; n < NF; n++) bF[n] = *(const i32x4*)&Bs[p][wn * (BN / 2) + n * 16 + lq][sa];
        if (prefetch) STAGE((p + 2) % 3, knext);
        __builtin_amdgcn_s_setprio(1);
#pragma unroll
        for (int m = 0; m < 4; m++)
#pragma unroll
            for (int n = 0; n < NF; n++)
                acc[m][n] = __builtin_amdgcn_mfma_i32_16x16x64_i8(aF[m], bF[n], acc[m][n], 0, 0, 0);
        __builtin_amdgcn_s_setprio(0);
    };

    const int nst = K >> 6;            // 12 or 48
    STAGE(0, 0);
    STAGE(1, 64);
#pragma unroll 1
    for (int t = 0; t < nst - 1; t++) {
        asm volatile("s_waitcnt vmcnt(%0)" :: "n"(L) : "memory");  // stage t complete
        __builtin_amdgcn_s_barrier();
        COMPUTE(t % 3, t + 2 < nst, (t + 2) << 6);
    }
    asm volatile("s_waitcnt vmcnt(0)" ::: "memory");
    __builtin_amdgcn_s_barrier();
    COMPUTE((nst - 1) % 3, false, 0);

    const int r0 = bm + wm * 64, c0 = bn + wn * (BN / 2);
#pragma unroll
    for (int m = 0; m < 4; m++) {
#pragma unroll
        for (int n = 0; n < NF; n++) {
            int c = c0 + n * 16 + lq;
#pragma unroll
            for (int i = 0; i < 4; i++) {
                int r = r0 + m * 16 + khi * 4 + i;
                int v = acc[m][n][i];
                if (EPI == EPI_SIGN) {
                    outB[(size_t)r * N + c] = (v >= 0) ? 1 : -1;
                } else if (EPI == EPI_RESID) {
                    float t = alpha[c] * ((float)v * ascale) + bias[c];
                    size_t idx = (size_t)r * N + c;
                    outF[idx] = resid[idx] + ls[c] * t;
                } else if (EPI == EPI_GELU) {
                    // per-row dequant, gelu (tanh-form via exp+rcp, err<0.004 << 1/16
                    // quant step; final-output contribution ~1e-5), i8 quant
                    float t = alpha[c] * ((float)v * rowscale[r]) + bias[c];
                    float y2 = 1.5957691f * t + 0.07135481f * t * t * t;
                    float ge = t * __builtin_amdgcn_rcpf(1.0f + __expf(-y2));
                    float qf = fminf(fmaxf(ge * MSCALE_INV, -127.f), 127.f);
                    outB[(size_t)r * N + c] = (signed char)__float2int_rn(qf);
                }
            }
            if (EPI == EPI_QKV) {
                // Q,K -> qk[token][1536]; V -> vt[(bh*64+d)*1024 + token] (u32-packed)
                if (c < 1536) {
#pragma unroll
                    for (int i = 0; i < 4; i++) {
                        int r = r0 + m * 16 + khi * 4 + i;
                        outB[(size_t)r * 1536 + c] = (acc[m][n][i] >= 0) ? 1 : -1;
                    }
                } else {
                    int rb = r0 + m * 16 + khi * 4;            // multiple of 4
                    int hh = (c - 1536) >> 6, dd = (c - 1536) & 63;
                    unsigned pk = 0;
#pragma unroll
                    for (int i = 0; i < 4; i++)
                        pk |= (unsigned)(unsigned char)((acc[m][n][i] >= 0) ? 1 : -1) << (8 * i);
                    *(unsigned*)(vtB + (((size_t)(rb >> 10) * NHEAD + hh) * 64 + dd) * SEQL + (rb & 1023)) = pk;
                }
            }
        }
    }
}

// ---------- binary attention v2 (exact i8) ----------
// mask = (Q.K^T > 0); O = mask @ V; emit sign(O).
// Grid: 96 (b,h) x 8 q-blocks of 128 rows. 4 waves x 32 q-rows.
__global__ void __launch_bounds__(256) attn_v2(const signed char* __restrict__ qk,
                                               const signed char* __restrict__ vt,
                                               signed char* __restrict__ a2) {
    const int id = blockIdx.x;                       // 0..767
    const int nid = (id & 7) * 96 + (id >> 3);
    const int bh = nid >> 3, qb = nid & 7;
    const int b = bh / NHEAD, h = bh % NHEAD;
    const int tid = threadIdx.x, ln = tid & 63, w = tid >> 6;
    const int lq = ln & 15, khi = ln >> 4;

    __shared__ signed char Ks[64][80];    // K tile: rows=kv token, 80B pad
    __shared__ signed char Vts[64][80];   // V^T tile: rows=d, cols=kv token
    __shared__ signed char Pw[4][32][80]; // per-wave P[q][m]

    const size_t tokbase = (size_t)b * SEQL;
    const int q0 = qb * 128 + w * 32;
    const int str = tid >> 2, stc = (tid & 3) * 16;
    const size_t vtrow = ((size_t)bh * 64 + str) * SEQL;

    i32x4 qfrag[2];
#pragma unroll
    for (int qf = 0; qf < 2; qf++)
        qfrag[qf] = *(const i32x4*)(qk + (tokbase + q0 + qf * 16 + lq) * 1536 + h * 64 + khi * 16);

    const i32x4 iz = {0, 0, 0, 0};
    i32x4 o[2][4];
#pragma unroll
    for (int qf = 0; qf < 2; qf++)
#pragma unroll
        for (int df = 0; df < 4; df++) o[qf][df] = iz;

    auto LOADJ = [&](int j, sc16& kr, sc16& vr) {
        kr = *(const sc16*)(qk + (tokbase + j * 64 + str) * 1536 + 768 + h * 64 + stc);
        vr = *(const sc16*)(vt + vtrow + j * 64 + stc);
    };
    auto STORE = [&](const sc16& kr, const sc16& vr) {
        *(sc16*)&Ks[str][stc] = kr;
        *(sc16*)&Vts[str][stc] = vr;
    };
    auto COMPUTE = [&]() {
        i32x4 kfrag[4];
#pragma unroll
        for (int kf = 0; kf < 4; kf++)
            kfrag[kf] = *(const i32x4*)&Ks[kf * 16 + lq][khi * 16];
#pragma unroll
        for (int kf = 0; kf < 4; kf++) {
#pragma unroll
            for (int qf = 0; qf < 2; qf++) {
                i32x4 st = __builtin_amdgcn_mfma_i32_16x16x64_i8(kfrag[kf], qfrag[qf], iz, 0, 0, 0);
                unsigned pb = (st[0] > 0 ? 1u : 0u) | (st[1] > 0 ? 0x100u : 0u) |
                              (st[2] > 0 ? 0x10000u : 0u) | (st[3] > 0 ? 0x1000000u : 0u);
                *(unsigned*)&Pw[w][qf * 16 + lq][kf * 16 + khi * 4] = pb;
            }
        }
        i32x4 pa[2];
#pragma unroll
        for (int qf = 0; qf < 2; qf++)
            pa[qf] = *(const i32x4*)&Pw[w][qf * 16 + lq][khi * 16];
#pragma unroll
        for (int df = 0; df < 4; df++) {
            i32x4 vfr = *(const i32x4*)&Vts[df * 16 + lq][khi * 16];
#pragma unroll
            for (int qf = 0; qf < 2; qf++)
                o[qf][df] = __builtin_amdgcn_mfma_i32_16x16x64_i8(pa[qf], vfr, o[qf][df], 0, 0, 0);
        }
    };

    sc16 ka, va, kb, vb;
    LOADJ(0, ka, va);
#pragma unroll 1
    for (int jj = 0; jj < 16; jj += 2) {
        __syncthreads();
        STORE(ka, va);
        __syncthreads();
        LOADJ(jj + 1, kb, vb);
        COMPUTE();
        __syncthreads();
        STORE(kb, vb);
        __syncthreads();
        if (jj + 2 < 16) LOADJ(jj + 2, ka, va);
        COMPUTE();
    }

#pragma unroll
    for (int qf = 0; qf < 2; qf++)
#pragma unroll
        for (int df = 0; df < 4; df++)
#pragma unroll
            for (int i = 0; i < 4; i++) {
                int qrow = q0 + qf * 16 + khi * 4 + i;
                int dim = df * 16 + lq;
                a2[(tokbase + qrow) * CDIM + h * 64 + dim] = (o[qf][df][i] >= 0) ? 1 : -1;
            }
}

// ---------- workspace layout (bytes) ----------
static const size_t OFF_WQKV  = 0;          // 2304*768   = 1769472
static const size_t OFF_WPROJ = 1769472;    // 768*768    = 589824
static const size_t OFF_WFC1  = 2359296;    // 3072*768   = 2359296
static const size_t OFF_WFC2  = 4718592;    // 768*3072   = 2359296
static const size_t OFF_APROJ = 7077888;    // 768*4
static const size_t OFF_AFC1  = 7080960;    // 3072*4
static const size_t OFF_AFC2  = 7093248;    // 768*4
static const size_t OFF_H2SC  = 7096320;    // 8192*4
static const size_t OFF_QK    = 7129088;    // 8192*1536  = 12582912
static const size_t OFF_VT    = 19712000;   // 96*64*1024 = 6291456
static const size_t OFF_A2    = 26003456;   // 8192*768   = 6291456
static const size_t OFF_A1    = 32294912;   // 8192*768   = 6291456
static const size_t OFF_M1    = 38586368;   // 8192*3072  = 25165824
static const size_t OFF_H2    = 63752192;   // 8192*768   = 6291456
// total = 70043648 bytes

extern "C" void kernel_launch(void* const* d_in, const int* in_sizes, int n_in,
                              void* d_out, int out_size, void* d_ws, size_t ws_size,
                              hipStream_t stream) {
    const float* x      = (const float*)d_in[0];
    const float* ln1_g  = (const float*)d_in[1];
    const float* ln1_b  = (const float*)d_in[2];
    const float* w_qkv  = (const float*)d_in[3];
    const float* w_proj = (const float*)d_in[4];
    const float* b_proj = (const float*)d_in[5];
    const float* ls1_g  = (const float*)d_in[6];
    const float* ln2_g  = (const float*)d_in[7];
    const float* ln2_b  = (const float*)d_in[8];
    const float* w_fc1  = (const float*)d_in[9];
    const float* b_fc1  = (const float*)d_in[10];
    const float* w_fc2  = (const float*)d_in[11];
    const float* b_fc2  = (const float*)d_in[12];
    const float* ls2_g  = (const float*)d_in[13];
    float* out = (float*)d_out;

    char* ws = (char*)d_ws;
    signed char* wqkv_s  = (signed char*)(ws + OFF_WQKV);
    signed char* wproj_s = (signed char*)(ws + OFF_WPROJ);
    signed char* wfc1_s  = (signed char*)(ws + OFF_WFC1);
    signed char* wfc2_s  = (signed char*)(ws + OFF_WFC2);
    float* a_proj  = (float*)(ws + OFF_APROJ);
    float* a_fc1   = (float*)(ws + OFF_AFC1);
    float* a_fc2   = (float*)(ws + OFF_AFC2);
    float* h2scale = (float*)(ws + OFF_H2SC);
    signed char* qk   = (signed char*)(ws + OFF_QK);
    signed char* vt   = (signed char*)(ws + OFF_VT);
    signed char* a2   = (signed char*)(ws + OFF_A2);
    signed char* a1   = (signed char*)(ws + OFF_A1);
    signed char* m1   = (signed char*)(ws + OFF_M1);
    signed char* h2   = (signed char*)(ws + OFF_H2);

    // weight prep
    sign_w_kernel<<<512, 256, 0, stream>>>(w_qkv, wqkv_s, NQKV * CDIM);
    signalpha_kernel<<<CDIM, 256, 0, stream>>>(w_proj, wproj_s, a_proj, CDIM);
    signalpha_kernel<<<HIDD, 256, 0, stream>>>(w_fc1,  wfc1_s,  a_fc1,  CDIM);
    signalpha_kernel<<<CDIM, 256, 0, stream>>>(w_fc2,  wfc2_s,  a_fc2,  HIDD);

    // LN1 + sign
    ln_sign_kernel<<<NTOK, 256, 0, stream>>>(x, ln1_g, ln1_b, a1);

    // QKV: sign(a1 @ wqkv^T); Q,K -> qk[8192][1536], V -> vt transposed
    gemm_i8<EPI_QKV, 128><<<dim3(NQKV / 128, NTOK / 128), 256, 0, stream>>>(
        a1, wqkv_s, NTOK, NQKV, CDIM, nullptr, nullptr, nullptr, nullptr, nullptr, 1.0f, nullptr, qk, vt);

    // binary attention -> sign(O) (exact i8)
    attn_v2<<<768, 256, 0, stream>>>(qk, vt, a2);

    // proj + layerscale residual: out(x1) = x + ls1*(alpha_proj*acc + b_proj)
    gemm_i8<EPI_RESID, 64><<<dim3(CDIM / 64, NTOK / 128), 256, 0, stream>>>(
        a2, wproj_s, NTOK, CDIM, CDIM, a_proj, b_proj, ls1_g, x, nullptr, 1.0f, out, nullptr, nullptr);

    // LN2 + per-row i8 quant (reads x1 from d_out)
    ln2q_kernel<<<NTOK, 256, 0, stream>>>(out, ln2_g, ln2_b, h2, h2scale);

    // fc1 + gelu -> fixed-scale i8
    gemm_i8<EPI_GELU, 128><<<dim3(HIDD / 128, NTOK / 128), 256, 0, stream>>>(
        h2, wfc1_s, NTOK, HIDD, CDIM, a_fc1, b_fc1, nullptr, nullptr, h2scale, 1.0f, nullptr, m1, nullptr);

    // fc2 + layerscale residual (in-place on d_out); dequant by 1/16
    gemm_i8<EPI_RESID, 64><<<dim3(CDIM / 64, NTOK / 128), 256, 0, stream>>>(
        m1, wfc2_s, NTOK, CDIM, HIDD, a_fc2, b_fc2, ls2_g, out, nullptr, 1.0f / MSCALE_INV, out, nullptr, nullptr);
}

// Round 7
// 170.850 us; speedup vs baseline: 2.0625x; 1.0441x over previous
//
#include <hip/hip_runtime.h>

// ---- problem constants ----
#define NTOK 8192      // B*N = 8*1024
#define CDIM 768
#define HIDD 3072
#define NQKV 2304
#define SEQL 1024
#define NHEAD 12

typedef int i32x4 __attribute__((ext_vector_type(4)));
typedef float f32x4 __attribute__((ext_vector_type(4)));
typedef signed char sc16 __attribute__((ext_vector_type(16)));

// async global->LDS, 16B per lane. Dest must be wave-uniform base + lane*16.
__device__ __forceinline__ void gload_lds16(const void* g, void* l) {
    __builtin_amdgcn_global_load_lds(
        (const __attribute__((address_space(1))) unsigned int*)g,
        (__attribute__((address_space(3))) unsigned int*)l, 16, 0, 0);
}

// sign(w) as i8 +-1 (x>=0 -> +1 per ste_sign)
__global__ void sign_w_kernel(const float* __restrict__ w, signed char* __restrict__ ws, int n) {
    int i = blockIdx.x * blockDim.x + threadIdx.x;
    int stride = gridDim.x * blockDim.x;
    for (; i < n; i += stride)
        ws[i] = (w[i] >= 0.0f) ? 1 : -1;
}

// fused: sign(w) i8 + alpha[row] = mean|w[row,:]|
// PERM: write k-index within each 64-group permuted by pi(j) = (j&15)*4 + (j>>4)
// (matches the MFMA C-fragment byte packing of the producer of the A operand).
template<bool PERM>
__global__ void __launch_bounds__(256) signalpha_kernel(const float* __restrict__ w,
                                                        signed char* __restrict__ ws,
                                                        float* __restrict__ alpha, int K) {
    int row = blockIdx.x;
    const float* wr = w + (size_t)row * K;
    signed char* wsr = ws + (size_t)row * K;
    float s = 0.f;
    for (int i = threadIdx.x; i < K; i += 256) {
        float v = wr[i];
        int ip = PERM ? ((i & ~63) | (((i & 15) << 2) | ((i >> 4) & 3))) : i;
        wsr[ip] = (v >= 0.f) ? 1 : -1;
        s += fabsf(v);
    }
    for (int off = 32; off > 0; off >>= 1) s += __shfl_down(s, off);
    __shared__ float red[4];
    if ((threadIdx.x & 63) == 0) red[threadIdx.x >> 6] = s;
    __syncthreads();
    if (threadIdx.x == 0) alpha[row] = (red[0] + red[1] + red[2] + red[3]) / (float)K;
}

// LayerNorm over 768 -> sign as i8 +-1 (for LN1 path)
__global__ void __launch_bounds__(256) ln_sign_kernel(const float* __restrict__ x, const float* __restrict__ g,
                                                      const float* __restrict__ b, signed char* __restrict__ out) {
    int row = blockIdx.x;
    const float* xr = x + (size_t)row * CDIM;
    float v0 = xr[threadIdx.x], v1 = xr[threadIdx.x + 256], v2 = xr[threadIdx.x + 512];
    float s = v0 + v1 + v2, s2 = v0 * v0 + v1 * v1 + v2 * v2;
    for (int off = 32; off > 0; off >>= 1) { s += __shfl_down(s, off); s2 += __shfl_down(s2, off); }
    __shared__ float red[8];
    if ((threadIdx.x & 63) == 0) { red[threadIdx.x >> 6] = s; red[4 + (threadIdx.x >> 6)] = s2; }
    __syncthreads();
    float ts = red[0] + red[1] + red[2] + red[3];
    float t2 = red[4] + red[5] + red[6] + red[7];
    float mu = ts * (1.0f / CDIM);
    float var = t2 * (1.0f / CDIM) - mu * mu;
    float rstd = rsqrtf(var + 1e-5f);
    signed char* orow = out + (size_t)row * CDIM;
    float vv[3] = {v0, v1, v2};
#pragma unroll
    for (int p = 0; p < 3; p++) {
        int i = threadIdx.x + p * 256;
        float val = (vv[p] - mu) * rstd * g[i] + b[i];
        orow[i] = (val >= 0.f) ? 1 : -1;
    }
}

// LayerNorm over 768 -> per-row i8 quant (for LN2/fc1 path); rowscale[row] = rowmax/127
__global__ void __launch_bounds__(256) ln2q_kernel(const float* __restrict__ x, const float* __restrict__ g,
                                                   const float* __restrict__ b, signed char* __restrict__ out,
                                                   float* __restrict__ rowscale) {
    int row = blockIdx.x;
    const float* xr = x + (size_t)row * CDIM;
    float v0 = xr[threadIdx.x], v1 = xr[threadIdx.x + 256], v2 = xr[threadIdx.x + 512];
    float s = v0 + v1 + v2, s2 = v0 * v0 + v1 * v1 + v2 * v2;
    for (int off = 32; off > 0; off >>= 1) { s += __shfl_down(s, off); s2 += __shfl_down(s2, off); }
    __shared__ float red[8];
    __shared__ float redm[4];
    if ((threadIdx.x & 63) == 0) { red[threadIdx.x >> 6] = s; red[4 + (threadIdx.x >> 6)] = s2; }
    __syncthreads();
    float ts = red[0] + red[1] + red[2] + red[3];
    float t2 = red[4] + red[5] + red[6] + red[7];
    float mu = ts * (1.0f / CDIM);
    float var = t2 * (1.0f / CDIM) - mu * mu;
    float rstd = rsqrtf(var + 1e-5f);
    float a0 = (v0 - mu) * rstd * g[threadIdx.x] + b[threadIdx.x];
    float a1 = (v1 - mu) * rstd * g[threadIdx.x + 256] + b[threadIdx.x + 256];
    float a2v = (v2 - mu) * rstd * g[threadIdx.x + 512] + b[threadIdx.x + 512];
    float mx = fmaxf(fabsf(a0), fmaxf(fabsf(a1), fabsf(a2v)));
    for (int off = 32; off > 0; off >>= 1) mx = fmaxf(mx, __shfl_down(mx, off));
    if ((threadIdx.x & 63) == 0) redm[threadIdx.x >> 6] = mx;
    __syncthreads();
    float rmax = fmaxf(fmaxf(redm[0], redm[1]), fmaxf(redm[2], redm[3]));
    rmax = fmaxf(rmax, 1e-20f);
    float inv = 127.f / rmax;
    signed char* orow = out + (size_t)row * CDIM;
    orow[threadIdx.x]       = (signed char)__float2int_rn(a0 * inv);
    orow[threadIdx.x + 256] = (signed char)__float2int_rn(a1 * inv);
    orow[threadIdx.x + 512] = (signed char)__float2int_rn(a2v * inv);
    if (threadIdx.x == 0) rowscale[row] = rmax * (1.f / 127.f);
}

// ---------- i8 GEMM: acc[M,N] = A[M,K] @ B[N,K]^T, i32 accum ----------
// 128xBN tile, 4 waves, 16x16x64 i8 MFMA, BK=64 bytes.
// 3-buffer LDS pipeline, counted vmcnt; XOR slot-swizzle; coalesced epilogues:
//  RESID: LDS-transpose -> float4 resid/out;  GELU/QKV: pi-packed u32 stores.
enum { EPI_RESID = 1, EPI_GELU = 2, EPI_QKV = 3 };
#define MSCALE_INV 16.0f    // gelu-out quant: q = round(ge*16), dequant acc * (1/16)

template<int EPI, int BN>
__global__ void __launch_bounds__(256) gemm_i8(
    const signed char* __restrict__ A, const signed char* __restrict__ B,
    int M, int N, int K,
    const float* __restrict__ alpha, const float* __restrict__ bias,
    const float* __restrict__ ls, const float* __restrict__ resid,
    const float* __restrict__ rowscale, float ascale,
    float* __restrict__ outF, signed char* __restrict__ outB,
    signed char* __restrict__ vtB)
{
    constexpr int STAGE_B = 3 * (128 + BN) * 64;
    static_assert(STAGE_B >= 128 * 68 * 4 || EPI != EPI_RESID, "epi lds fits");
    __shared__ __align__(16) char lds_raw[STAGE_B];
    auto As = (signed char (*)[128][64])lds_raw;
    auto Bs = (signed char (*)[BN][64])(lds_raw + 3 * 128 * 64);

    const int tid = threadIdx.x, ln = tid & 63, w = tid >> 6;
    const int wm = w >> 1, wn = w & 1;
    const int lq = ln & 15, khi = ln >> 4;
    constexpr int NF = BN / 32;                  // n-frags per wave
    constexpr int L = (BN == 128) ? 4 : 3;       // gload_lds per stage per thread

    // XCD-chunked bijective swizzle (all grids divisible by 8)
    const int nwg = gridDim.x * gridDim.y;
    const int id = blockIdx.y * gridDim.x + blockIdx.x;
    const int nid = (id & 7) * (nwg >> 3) + (id >> 3);
    const int bxs = nid % gridDim.x, bys = nid / gridDim.x;
    const int bm = bys * 128, bn = bxs * BN;

    const i32x4 iz = {0, 0, 0, 0};
    i32x4 acc[4][NF];
#pragma unroll
    for (int m = 0; m < 4; m++)
#pragma unroll
        for (int n = 0; n < NF; n++) acc[m][n] = iz;

    const int srow = tid >> 2, scol = (tid & 3) * 16;
    const int ssrc = ((tid & 3) ^ ((srow >> 1) & 3)) * 16;   // pre-swizzled global slot
    const int sa = 16 * (khi ^ ((lq >> 1) & 3));             // swizzled LDS read slot

    auto STAGE = [&](int p, int k0) {
        gload_lds16(A + (size_t)(bm + srow) * K + k0 + ssrc, &As[p][srow][scol]);
        gload_lds16(A + (size_t)(bm + 64 + srow) * K + k0 + ssrc, &As[p][64 + srow][scol]);
        gload_lds16(B + (size_t)(bn + srow) * K + k0 + ssrc, &Bs[p][srow][scol]);
        if constexpr (BN == 128)
            gload_lds16(B + (size_t)(bn + 64 + srow) * K + k0 + ssrc, &Bs[p][64 + srow][scol]);
    };
    auto COMPUTE = [&](int p, bool prefetch, int knext) {
        i32x4 aF[4], bF[NF];
#pragma unroll
        for (int m = 0; m < 4; m++) aF[m] = *(const i32x4*)&As[p][wm * 64 + m * 16 + lq][sa];
#pragma unroll
        for (int n = 0; n < NF; n++) bF[n] = *(const i32x4*)&Bs[p][wn * (BN / 2) + n * 16 + lq][sa];
        if (prefetch) STAGE((p + 2) % 3, knext);
        __builtin_amdgcn_s_setprio(1);
#pragma unroll
        for (int m = 0; m < 4; m++)
#pragma unroll
            for (int n = 0; n < NF; n++)
                acc[m][n] = __builtin_amdgcn_mfma_i32_16x16x64_i8(aF[m], bF[n], acc[m][n], 0, 0, 0);
        __builtin_amdgcn_s_setprio(0);
    };

    const int nst = K >> 6;            // 12 or 48
    STAGE(0, 0);
    STAGE(1, 64);
#pragma unroll 1
    for (int t = 0; t < nst - 1; t++) {
        asm volatile("s_waitcnt vmcnt(%0)" :: "n"(L) : "memory");  // stage t complete
        __builtin_amdgcn_s_barrier();
        COMPUTE(t % 3, t + 2 < nst, (t + 2) << 6);
    }
    asm volatile("s_waitcnt vmcnt(0)" ::: "memory");
    __builtin_amdgcn_s_barrier();
    COMPUTE((nst - 1) % 3, false, 0);

    const int r0 = bm + wm * 64, c0loc = wn * (BN / 2);

    if constexpr (EPI == EPI_RESID) {
        // stage f32 C through LDS, then fully-coalesced float4 resid+out
        __syncthreads();
        float (*Cf)[68] = (float (*)[68])lds_raw;   // 128x68 pad: 2-way banks max
#pragma unroll
        for (int m = 0; m < 4; m++)
#pragma unroll
            for (int n = 0; n < NF; n++)
#pragma unroll
                for (int i = 0; i < 4; i++)
                    Cf[wm * 64 + m * 16 + khi * 4 + i][c0loc + n * 16 + lq] =
                        (float)acc[m][n][i] * ascale;
        __syncthreads();
#pragma unroll
        for (int p = 0; p < 8; p++) {
            int idx = p * 256 + tid;
            int row = idx >> 4, c4 = (idx & 15) * 4;
            f32x4 a4 = *(const f32x4*)&alpha[bn + c4];
            f32x4 b4 = *(const f32x4*)&bias[bn + c4];
            f32x4 l4 = *(const f32x4*)&ls[bn + c4];
            f32x4 v4 = *(const f32x4*)&Cf[row][c4];
            size_t g = (size_t)(bm + row) * N + bn + c4;
            f32x4 r4 = *(const f32x4*)&resid[g];
            f32x4 o4 = r4 + l4 * (a4 * v4 + b4);
            *(f32x4*)&outF[g] = o4;
        }
    } else if constexpr (EPI == EPI_GELU) {
        // pi-packed u32 stores into permuted hidden layout (wfc2 matches)
        float al[NF], bi[NF];
#pragma unroll
        for (int n = 0; n < NF; n++) {
            int c = bn + c0loc + n * 16 + lq;
            al[n] = alpha[c]; bi[n] = bias[c];
        }
#pragma unroll
        for (int m = 0; m < 4; m++)
#pragma unroll
            for (int i = 0; i < 4; i++) {
                int r = r0 + m * 16 + khi * 4 + i;
                float rs = rowscale[r];
                unsigned pk = 0;
#pragma unroll
                for (int n = 0; n < NF; n++) {
                    float t = al[n] * ((float)acc[m][n][i] * rs) + bi[n];
                    float y2 = 1.5957691f * t + 0.07135481f * t * t * t;
                    float ge = t * __builtin_amdgcn_rcpf(1.0f + __expf(-y2));
                    float qf = fminf(fmaxf(ge * MSCALE_INV, -127.f), 127.f);
                    pk |= (unsigned)(unsigned char)(signed char)__float2int_rn(qf) << (8 * n);
                }
                *(unsigned*)(outB + (size_t)r * N + bn + c0loc + lq * 4) = pk;
            }
    } else {  // EPI_QKV
        if (bn < 1536) {
            // Q,K: pi-packed u32 (Q and K share the permutation -> QK^T exact)
#pragma unroll
            for (int m = 0; m < 4; m++)
#pragma unroll
                for (int i = 0; i < 4; i++) {
                    int r = r0 + m * 16 + khi * 4 + i;
                    unsigned pk = 0;
#pragma unroll
                    for (int n = 0; n < NF; n++)
                        pk |= (unsigned)(unsigned char)(signed char)((acc[m][n][i] >= 0) ? 1 : -1) << (8 * n);
                    *(unsigned*)(outB + (size_t)r * 1536 + bn + c0loc + lq * 4) = pk;
                }
        } else {
            // V -> vt[(b*12+hh)*64+dd][token], token-packed u32 (true d kept)
#pragma unroll
            for (int m = 0; m < 4; m++)
#pragma unroll
                for (int n = 0; n < NF; n++) {
                    int cg = bn + c0loc + n * 16 + lq - 1536;
                    int hh = cg >> 6, dd = cg & 63;
                    int rb = r0 + m * 16 + khi * 4;
                    unsigned pk = 0;
#pragma unroll
                    for (int i = 0; i < 4; i++)
                        pk |= (unsigned)(unsigned char)(signed char)((acc[m][n][i] >= 0) ? 1 : -1) << (8 * i);
                    *(unsigned*)(vtB + (((size_t)(rb >> 10) * NHEAD + hh) * 64 + dd) * SEQL + (rb & 1023)) = pk;
                }
        }
    }
}

// ---------- binary attention v2 (exact i8) ----------
// mask = (Q.K^T > 0); O = mask @ V; emit sign(O) pi-packed (wproj matches).
// Grid: 96 (b,h) x 8 q-blocks of 128 rows. 4 waves x 32 q-rows.
__global__ void __launch_bounds__(256) attn_v2(const signed char* __restrict__ qk,
                                               const signed char* __restrict__ vt,
                                               signed char* __restrict__ a2) {
    const int id = blockIdx.x;                       // 0..767
    const int nid = (id & 7) * 96 + (id >> 3);
    const int bh = nid >> 3, qb = nid & 7;
    const int b = bh / NHEAD, h = bh % NHEAD;
    const int tid = threadIdx.x, ln = tid & 63, w = tid >> 6;
    const int lq = ln & 15, khi = ln >> 4;

    __shared__ signed char Ks[64][80];    // K tile: rows=kv token, 80B pad
    __shared__ signed char Vts[64][80];   // V^T tile: rows=d, cols=kv token
    __shared__ signed char Pw[4][32][80]; // per-wave P[q][m]

    const size_t tokbase = (size_t)b * SEQL;
    const int q0 = qb * 128 + w * 32;
    const int str = tid >> 2, stc = (tid & 3) * 16;
    const size_t vtrow = ((size_t)bh * 64 + str) * SEQL;

    i32x4 qfrag[2];
#pragma unroll
    for (int qf = 0; qf < 2; qf++)
        qfrag[qf] = *(const i32x4*)(qk + (tokbase + q0 + qf * 16 + lq) * 1536 + h * 64 + khi * 16);

    const i32x4 iz = {0, 0, 0, 0};
    i32x4 o[2][4];
#pragma unroll
    for (int qf = 0; qf < 2; qf++)
#pragma unroll
        for (int df = 0; df < 4; df++) o[qf][df] = iz;

    auto LOADJ = [&](int j, sc16& kr, sc16& vr) {
        kr = *(const sc16*)(qk + (tokbase + j * 64 + str) * 1536 + 768 + h * 64 + stc);
        vr = *(const sc16*)(vt + vtrow + j * 64 + stc);
    };
    auto STORE = [&](const sc16& kr, const sc16& vr) {
        *(sc16*)&Ks[str][stc] = kr;
        *(sc16*)&Vts[str][stc] = vr;
    };
    auto COMPUTE = [&]() {
        i32x4 kfrag[4];
#pragma unroll
        for (int kf = 0; kf < 4; kf++)
            kfrag[kf] = *(const i32x4*)&Ks[kf * 16 + lq][khi * 16];
#pragma unroll
        for (int kf = 0; kf < 4; kf++) {
#pragma unroll
            for (int qf = 0; qf < 2; qf++) {
                i32x4 st = __builtin_amdgcn_mfma_i32_16x16x64_i8(kfrag[kf], qfrag[qf], iz, 0, 0, 0);
                unsigned pb = (st[0] > 0 ? 1u : 0u) | (st[1] > 0 ? 0x100u : 0u) |
                              (st[2] > 0 ? 0x10000u : 0u) | (st[3] > 0 ? 0x1000000u : 0u);
                *(unsigned*)&Pw[w][qf * 16 + lq][kf * 16 + khi * 4] = pb;
            }
        }
        i32x4 pa[2];
#pragma unroll
        for (int qf = 0; qf < 2; qf++)
            pa[qf] = *(const i32x4*)&Pw[w][qf * 16 + lq][khi * 16];
#pragma unroll
        for (int df = 0; df < 4; df++) {
            i32x4 vfr = *(const i32x4*)&Vts[df * 16 + lq][khi * 16];
#pragma unroll
            for (int qf = 0; qf < 2; qf++)
                o[qf][df] = __builtin_amdgcn_mfma_i32_16x16x64_i8(pa[qf], vfr, o[qf][df], 0, 0, 0);
        }
    };

    sc16 ka, va, kb, vb;
    LOADJ(0, ka, va);
#pragma unroll 1
    for (int jj = 0; jj < 16; jj += 2) {
        __syncthreads();
        STORE(ka, va);
        __syncthreads();
        LOADJ(jj + 1, kb, vb);
        COMPUTE();
        __syncthreads();
        STORE(kb, vb);
        __syncthreads();
        if (jj + 2 < 16) LOADJ(jj + 2, ka, va);
        COMPUTE();
    }

    // epilogue: pi-packed u32: a2[token][h*64 + lq*4 + df] = sign(O[. ][df*16+lq])
#pragma unroll
    for (int qf = 0; qf < 2; qf++)
#pragma unroll
        for (int i = 0; i < 4; i++) {
            int qrow = q0 + qf * 16 + khi * 4 + i;
            unsigned pk = 0;
#pragma unroll
            for (int df = 0; df < 4; df++)
                pk |= (unsigned)(unsigned char)(signed char)((o[qf][df][i] >= 0) ? 1 : -1) << (8 * df);
            *(unsigned*)(a2 + (tokbase + qrow) * CDIM + h * 64 + lq * 4) = pk;
        }
}

// ---------- workspace layout (bytes) ----------
static const size_t OFF_WQKV  = 0;          // 2304*768   = 1769472
static const size_t OFF_WPROJ = 1769472;    // 768*768    = 589824
static const size_t OFF_WFC1  = 2359296;    // 3072*768   = 2359296
static const size_t OFF_WFC2  = 4718592;    // 768*3072   = 2359296
static const size_t OFF_APROJ = 7077888;    // 768*4
static const size_t OFF_AFC1  = 7080960;    // 3072*4
static const size_t OFF_AFC2  = 7093248;    // 768*4
static const size_t OFF_H2SC  = 7096320;    // 8192*4
static const size_t OFF_QK    = 7129088;    // 8192*1536  = 12582912
static const size_t OFF_VT    = 19712000;   // 96*64*1024 = 6291456
static const size_t OFF_A2    = 26003456;   // 8192*768   = 6291456
static const size_t OFF_A1    = 32294912;   // 8192*768   = 6291456
static const size_t OFF_M1    = 38586368;   // 8192*3072  = 25165824
static const size_t OFF_H2    = 63752192;   // 8192*768   = 6291456
// total = 70043648 bytes

extern "C" void kernel_launch(void* const* d_in, const int* in_sizes, int n_in,
                              void* d_out, int out_size, void* d_ws, size_t ws_size,
                              hipStream_t stream) {
    const float* x      = (const float*)d_in[0];
    const float* ln1_g  = (const float*)d_in[1];
    const float* ln1_b  = (const float*)d_in[2];
    const float* w_qkv  = (const float*)d_in[3];
    const float* w_proj = (const float*)d_in[4];
    const float* b_proj = (const float*)d_in[5];
    const float* ls1_g  = (const float*)d_in[6];
    const float* ln2_g  = (const float*)d_in[7];
    const float* ln2_b  = (const float*)d_in[8];
    const float* w_fc1  = (const float*)d_in[9];
    const float* b_fc1  = (const float*)d_in[10];
    const float* w_fc2  = (const float*)d_in[11];
    const float* b_fc2  = (const float*)d_in[12];
    const float* ls2_g  = (const float*)d_in[13];
    float* out = (float*)d_out;

    char* ws = (char*)d_ws;
    signed char* wqkv_s  = (signed char*)(ws + OFF_WQKV);
    signed char* wproj_s = (signed char*)(ws + OFF_WPROJ);
    signed char* wfc1_s  = (signed char*)(ws + OFF_WFC1);
    signed char* wfc2_s  = (signed char*)(ws + OFF_WFC2);
    float* a_proj  = (float*)(ws + OFF_APROJ);
    float* a_fc1   = (float*)(ws + OFF_AFC1);
    float* a_fc2   = (float*)(ws + OFF_AFC2);
    float* h2scale = (float*)(ws + OFF_H2SC);
    signed char* qk   = (signed char*)(ws + OFF_QK);
    signed char* vt   = (signed char*)(ws + OFF_VT);
    signed char* a2   = (signed char*)(ws + OFF_A2);
    signed char* a1   = (signed char*)(ws + OFF_A1);
    signed char* m1   = (signed char*)(ws + OFF_M1);
    signed char* h2   = (signed char*)(ws + OFF_H2);

    // weight prep (wproj/wfc2 k-dims pi-permuted to match a2/m1 producers)
    sign_w_kernel<<<512, 256, 0, stream>>>(w_qkv, wqkv_s, NQKV * CDIM);
    signalpha_kernel<true><<<CDIM, 256, 0, stream>>>(w_proj, wproj_s, a_proj, CDIM);
    signalpha_kernel<false><<<HIDD, 256, 0, stream>>>(w_fc1,  wfc1_s,  a_fc1,  CDIM);
    signalpha_kernel<true><<<CDIM, 256, 0, stream>>>(w_fc2,  wfc2_s,  a_fc2,  HIDD);

    // LN1 + sign
    ln_sign_kernel<<<NTOK, 256, 0, stream>>>(x, ln1_g, ln1_b, a1);

    // QKV: sign(a1 @ wqkv^T); Q,K -> qk[8192][1536] (pi-packed), V -> vt transposed
    gemm_i8<EPI_QKV, 128><<<dim3(NQKV / 128, NTOK / 128), 256, 0, stream>>>(
        a1, wqkv_s, NTOK, NQKV, CDIM, nullptr, nullptr, nullptr, nullptr, nullptr, 1.0f, nullptr, qk, vt);

    // binary attention -> sign(O) (exact i8)
    attn_v2<<<768, 256, 0, stream>>>(qk, vt, a2);

    // proj + layerscale residual: out(x1) = x + ls1*(alpha_proj*acc + b_proj)
    gemm_i8<EPI_RESID, 64><<<dim3(CDIM / 64, NTOK / 128), 256, 0, stream>>>(
        a2, wproj_s, NTOK, CDIM, CDIM, a_proj, b_proj, ls1_g, x, nullptr, 1.0f, out, nullptr, nullptr);

    // LN2 + per-row i8 quant (reads x1 from d_out)
    ln2q_kernel<<<NTOK, 256, 0, stream>>>(out, ln2_g, ln2_b, h2, h2scale);

    // fc1 + gelu -> fixed-scale i8 (pi-packed hidden layout)
    gemm_i8<EPI_GELU, 128><<<dim3(HIDD / 128, NTOK / 128), 256, 0, stream>>>(
        h2, wfc1_s, NTOK, HIDD, CDIM, a_fc1, b_fc1, nullptr, nullptr, h2scale, 1.0f, nullptr, m1, nullptr);

    // fc2 + layerscale residual (in-place on d_out); dequant by 1/16
    gemm_i8<EPI_RESID, 64><<<dim3(CDIM / 64, NTOK / 128), 256, 0, stream>>>(
        m1, wfc2_s, NTOK, CDIM, HIDD, a_fc2, b_fc2, ls2_g, out, nullptr, 1.0f / MSCALE_INV, out, nullptr, nullptr);
}